// Round 7
// baseline (358.151 us; speedup 1.0000x reference)
//
#include <hip/hip_runtime.h>
#include <hip/hip_bf16.h>
#include <math.h>

// ---- problem constants ----
#define BB 2
#define HH 50
#define WW 50
#define NN 2500            // H*W
#define PP 4
#define LRELU_SLOPE 0.2f
#define ZTOL 1e-9f
#define PXB2 10            // ceil(2500/256)
#define SEGS 5             // adjacency segments per row
#define SEGCAP 32          // slots per segment
#define SEGSTRIDE (SEGS * SEGCAP)   // 160

static inline int cdiv(int a, int b) { return (a + b - 1) / b; }

__device__ __forceinline__ float sigmoidf_(float v) { return 1.0f / (1.0f + expf(-v)); }

// ---------- weight repack: w[oc][ic][tap] -> wre[(ic*9+tap)*OC + oc] ----------
__global__ void k_repack(const float* __restrict__ e1, const float* __restrict__ e2,
                         const float* __restrict__ dd1, const float* __restrict__ dd2,
                         float* __restrict__ r1, float* __restrict__ r2,
                         float* __restrict__ r3, float* __restrict__ r4) {
    int i = blockIdx.x * blockDim.x + threadIdx.x;
    if (i < 32 * 3 * 9)  { int oc = i / 27;  int rem = i % 27;  int ic = rem / 9; int tp = rem % 9; r1[(ic * 9 + tp) * 32 + oc] = e1[i]; }
    if (i < 32 * 32 * 9) { int oc = i / 288; int rem = i % 288; int ic = rem / 9; int tp = rem % 9; r2[(ic * 9 + tp) * 32 + oc] = e2[i]; }
    if (i < 32 * 128 * 9){ int oc = i / 1152;int rem = i % 1152;int ic = rem / 9; int tp = rem % 9; r3[(ic * 9 + tp) * 32 + oc] = dd1[i]; }
    if (i < 1 * 32 * 9)  { int oc = 0;       int rem = i;       int ic = rem / 9; int tp = rem % 9; r4[(ic * 9 + tp) * 1  + oc] = dd2[i]; }
}

// ---------- enc conv1 (3->32) with fused sigmoid ----------
__launch_bounds__(256)
__global__ void k_conv_enc1(const float* __restrict__ x, const float* __restrict__ wre,
                            const float* __restrict__ bias, float* __restrict__ out) {
    int bx = blockIdx.x;
    int pxb = bx % PXB2;
    int ocg = (bx / PXB2) % 4;
    int b = bx / (PXB2 * 4);
    int px = pxb * 256 + threadIdx.x;
    bool valid = px < NN;
    int xx0 = px % WW, yy0 = px / WW;
    float acc[8];
#pragma unroll
    for (int o = 0; o < 8; ++o) acc[o] = 0.f;
    for (int ic = 0; ic < 3; ++ic) {
        const float* ip = x + ((size_t)(b * 3 + ic)) * NN;
        float v[9];
#pragma unroll
        for (int ky = 0; ky < 3; ++ky) {
            int yy = yy0 + ky - 1;
#pragma unroll
            for (int kx = 0; kx < 3; ++kx) {
                int xx = xx0 + kx - 1;
                bool ok = valid && yy >= 0 && yy < HH && xx >= 0 && xx < WW;
                v[ky * 3 + kx] = ok ? sigmoidf_(ip[yy * WW + xx]) : 0.f;
            }
        }
        const float* wp = wre + (size_t)ic * 9 * 32 + ocg * 8;
#pragma unroll
        for (int tp = 0; tp < 9; ++tp) {
            float vv = v[tp];
#pragma unroll
            for (int o = 0; o < 8; ++o) acc[o] += wp[tp * 32 + o] * vv;
        }
    }
    if (valid) {
#pragma unroll
        for (int o = 0; o < 8; ++o) {
            int oc = ocg * 8 + o;
            out[((size_t)(b * 32 + oc)) * NN + px] = fmaxf(acc[o] + bias[oc], 0.f);
        }
    }
}

// ---------- generic chunked conv3x3 partials ----------
template<int OCT>
__launch_bounds__(256)
__global__ void k_conv_part(const float* __restrict__ in, const float* __restrict__ wre,
                            const float* __restrict__ attscale,
                            float* __restrict__ part, int Cin, int OC, int nocg,
                            int nchunks, int icchunk, float padval) {
    int bx = blockIdx.x;
    int pxb = bx % PXB2; bx /= PXB2;
    int ocg = bx % nocg; bx /= nocg;
    int chunk = bx % nchunks;
    int b = bx / nchunks;
    int px = pxb * 256 + threadIdx.x;
    bool valid = px < NN;
    int xx0 = px % WW, yy0 = px / WW;

    float acc[OCT];
#pragma unroll
    for (int o = 0; o < OCT; ++o) acc[o] = 0.f;

    int ic0 = chunk * icchunk;
    int ic1 = ic0 + icchunk; if (ic1 > Cin) ic1 = Cin;

    for (int ic = ic0; ic < ic1; ++ic) {
        const float* ip = in + ((size_t)(b * Cin + ic)) * NN;
        float attv = attscale ? attscale[b * Cin + ic] : 1.f;
        float v[9];
#pragma unroll
        for (int ky = 0; ky < 3; ++ky) {
            int yy = yy0 + ky - 1;
#pragma unroll
            for (int kx = 0; kx < 3; ++kx) {
                int xx = xx0 + kx - 1;
                bool ok = valid && yy >= 0 && yy < HH && xx >= 0 && xx < WW;
                v[ky * 3 + kx] = ok ? ip[yy * WW + xx] * attv : padval;
            }
        }
        const float* wp = wre + (size_t)ic * 9 * OC + ocg * OCT;
#pragma unroll
        for (int tp = 0; tp < 9; ++tp) {
            float vv = v[tp];
#pragma unroll
            for (int o = 0; o < OCT; ++o) acc[o] += wp[tp * OC + o] * vv;
        }
    }
    if (valid) {
#pragma unroll
        for (int o = 0; o < OCT; ++o)
            part[(((size_t)chunk * BB + b) * OC + ocg * OCT + o) * NN + px] = acc[o];
    }
}

// ---------- reduce chunks + bias + relu; dual-layout write ----------
__global__ void k_conv_reduce(const float* __restrict__ part, const float* __restrict__ bias,
                              float* __restrict__ out, float* __restrict__ xTout,
                              int OCr, int nchunks) {
    int idx = blockIdx.x * blockDim.x + threadIdx.x;
    int total = BB * OCr * NN;
    if (idx >= total) return;
    int px = idx % NN;
    int oc = (idx / NN) % OCr;
    int b = idx / (NN * OCr);
    float s = bias[oc];
    for (int c = 0; c < nchunks; ++c)
        s += part[(((size_t)c * BB + b) * OCr + oc) * NN + px];
    s = fmaxf(s, 0.f);
    if (out)   out[((size_t)(b * OCr + oc)) * NN + px] = s;
    if (xTout) xTout[((size_t)b * NN + px) * OCr + oc] = s;
}

// ---------- segmented adjacency build: wave = (row, seg of 125 quads) ----------
__launch_bounds__(256)
__global__ void k_build_adj(const float* __restrict__ S,
                            unsigned long long* __restrict__ segb,
                            int* __restrict__ cols, float* __restrict__ vals) {
    int wg = blockIdx.x * 4 + (threadIdx.x >> 6);
    int lane = threadIdx.x & 63;
    int row = wg / SEGS;
    int seg = wg % SEGS;
    if (row >= 2 * BB * NN) return;
    int i = row % NN;
    int b = (row / NN) % BB;
    int s = row / (NN * BB);
    const float4* Srow = (const float4*)(S + (((size_t)(b * 2 + s)) * NN + i) * NN);
    int qb = seg * 125;

    float4 f1 = Srow[qb + lane];
    bool l2ok = lane < 61;
    float4 f2 = make_float4(0.f, 0.f, 0.f, 0.f);
    if (l2ok) f2 = Srow[qb + 64 + lane];

    unsigned long long below = (lane == 63) ? 0x7fffffffffffffffull
                                            : ((1ull << lane) - 1ull);
    unsigned long long a0 = __ballot(fabsf(f1.x) > ZTOL);
    unsigned long long a1 = __ballot(fabsf(f1.y) > ZTOL);
    unsigned long long a2 = __ballot(fabsf(f1.z) > ZTOL);
    unsigned long long a3 = __ballot(fabsf(f1.w) > ZTOL);
    unsigned long long c0 = __ballot(l2ok && fabsf(f2.x) > ZTOL);
    unsigned long long c1 = __ballot(l2ok && fabsf(f2.y) > ZTOL);
    unsigned long long c2 = __ballot(l2ok && fabsf(f2.z) > ZTOL);
    unsigned long long c3 = __ballot(l2ok && fabsf(f2.w) > ZTOL);

    int n1 = __popcll(a0) + __popcll(a1) + __popcll(a2) + __popcll(a3);
    int total = n1 + __popcll(c0) + __popcll(c1) + __popcll(c2) + __popcll(c3);

    size_t base = (size_t)row * SEGSTRIDE + seg * SEGCAP;
    {
        int idx = __popcll(a0 & below) + __popcll(a1 & below) +
                  __popcll(a2 & below) + __popcll(a3 & below);
        int j0 = (qb + lane) * 4;
        if ((a0 >> lane) & 1) { if (idx < SEGCAP) { cols[base + idx] = j0 + 0; vals[base + idx] = f1.x; } ++idx; }
        if ((a1 >> lane) & 1) { if (idx < SEGCAP) { cols[base + idx] = j0 + 1; vals[base + idx] = f1.y; } ++idx; }
        if ((a2 >> lane) & 1) { if (idx < SEGCAP) { cols[base + idx] = j0 + 2; vals[base + idx] = f1.z; } ++idx; }
        if ((a3 >> lane) & 1) { if (idx < SEGCAP) { cols[base + idx] = j0 + 3; vals[base + idx] = f1.w; } ++idx; }
    }
    {
        int idx = n1 + __popcll(c0 & below) + __popcll(c1 & below) +
                       __popcll(c2 & below) + __popcll(c3 & below);
        int j1 = (qb + 64 + lane) * 4;
        if ((c0 >> lane) & 1) { if (idx < SEGCAP) { cols[base + idx] = j1 + 0; vals[base + idx] = f2.x; } ++idx; }
        if ((c1 >> lane) & 1) { if (idx < SEGCAP) { cols[base + idx] = j1 + 1; vals[base + idx] = f2.y; } ++idx; }
        if ((c2 >> lane) & 1) { if (idx < SEGCAP) { cols[base + idx] = j1 + 2; vals[base + idx] = f2.z; } ++idx; }
        if ((c3 >> lane) & 1) { if (idx < SEGCAP) { cols[base + idx] = j1 + 3; vals[base + idx] = f2.w; } ++idx; }
    }
    if (lane == 0) {
        int t = total > SEGCAP ? SEGCAP : total;
        ((unsigned char*)segb)[(size_t)row * 8 + seg] = (unsigned char)t;
    }
}

// ---------- adjacency reader ----------
__device__ __forceinline__ void adj_load(const unsigned long long* __restrict__ segb,
                                         const int* __restrict__ cols,
                                         const float* __restrict__ vals,
                                         int node, int lane,
                                         int& cnt, int& colr, float& valr) {
    unsigned long long sb = segb[node];
    int c0 = (int)(sb & 0xff), c1 = (int)((sb >> 8) & 0xff), c2 = (int)((sb >> 16) & 0xff),
        c3 = (int)((sb >> 24) & 0xff), c4 = (int)((sb >> 32) & 0xff);
    int cum1 = c0, cum2 = cum1 + c1, cum3 = cum2 + c2, cum4 = cum3 + c3;
    cnt = cum4 + c4; if (cnt > 64) cnt = 64;
    int seg = 0, basec = 0;
    if (lane >= cum1) { seg = 1; basec = cum1; }
    if (lane >= cum2) { seg = 2; basec = cum2; }
    if (lane >= cum3) { seg = 3; basec = cum3; }
    if (lane >= cum4) { seg = 4; basec = cum4; }
    colr = 0; valr = 0.f;
    if (lane < cnt) {
        size_t sl = (size_t)node * SEGSTRIDE + seg * SEGCAP + (lane - basec);
        colr = cols[sl];
        valr = vals[sl];
    }
}

// ---------- per-head masked softmax * S ----------
__device__ __forceinline__ float4 softmax4(float4 s1f, float4 s2f, int lane, int cnt, float valr) {
    float e[PP] = { s1f.x + s2f.x, s1f.y + s2f.y, s1f.z + s2f.z, s1f.w + s2f.w };
    float w[PP];
#pragma unroll
    for (int p = 0; p < PP; ++p) {
        float v = e[p];
        v = (v < 0.f) ? LRELU_SLOPE * v : v;
        v = (lane < cnt) ? v : -1e30f;
        float mx = v;
#pragma unroll
        for (int m = 32; m >= 1; m >>= 1) mx = fmaxf(mx, __shfl_xor(mx, m));
        float ex = (lane < cnt) ? expf(v - mx) : 0.f;
        float sm = ex;
#pragma unroll
        for (int m = 32; m >= 1; m >>= 1) sm += __shfl_xor(sm, m);
        w[p] = (cnt > 0) ? ex / sm * valr : 0.f;
    }
    return make_float4(w[0], w[1], w[2], w[3]);
}

// ---------- emit s1/s2 from register y (lane holds output element `lane`) ----------
template<int PF>
__device__ __forceinline__ void emit_one(const float* __restrict__ a,
                                         float4* __restrict__ s1E, float4* __restrict__ s2E,
                                         float yl, int lane, int node) {
    float r1[PP], r2[PP];
#pragma unroll
    for (int p = 0; p < PP; ++p) {
        float v1 = (lane < PF) ? a[p * 2 * PF + lane] * yl : 0.f;
        float v2 = (lane < PF) ? a[p * 2 * PF + PF + lane] * yl : 0.f;
#pragma unroll
        for (int m = 32; m >= 1; m >>= 1) { v1 += __shfl_xor(v1, m); v2 += __shfl_xor(v2, m); }
        r1[p] = v1; r2[p] = v2;
    }
    if (lane == 0) {
        s1E[node] = make_float4(r1[0], r1[1], r1[2], r1[3]);
        s2E[node] = make_float4(r2[0], r2[1], r2[2], r2[3]);
    }
}

// ---------- GAT single: 4 INDEPENDENT waves per block (no barriers) ----------
template<int G, int F, int ES>
__launch_bounds__(256)
__global__ void k_gat_wave(const float* __restrict__ xT,
                           const unsigned long long* __restrict__ segb,
                           const int* __restrict__ cols, const float* __restrict__ vals,
                           const float4* __restrict__ s1T, const float4* __restrict__ s2T,
                           const float* __restrict__ Wf, const float* __restrict__ bias,
                           const float* __restrict__ aE0, float4* __restrict__ s1E0, float4* __restrict__ s2E0,
                           const float* __restrict__ aE1, float4* __restrict__ s1E1, float4* __restrict__ s2E1,
                           float* __restrict__ dst, int layout) {
    constexpr int PF = PP * F;
    __shared__ int    csh[4][64];
    __shared__ float4 wsh4[4][64];
    __shared__ float  xish[4][G];
    __shared__ float  z1sh[4][PP][G];

    int w = threadIdx.x >> 6;
    int lane = threadIdx.x & 63;
    int node = blockIdx.x * 4 + w;
    int b = node / NN, i = node % NN;

    if (lane < G) xish[w][lane] = xT[(size_t)node * G + lane];
    int cnt, colr; float valr;
    adj_load(segb, cols, vals, node, lane, cnt, colr, valr);
    float4 s1f = s1T[node];
    float4 s2f = make_float4(0.f, 0.f, 0.f, 0.f);
    if (lane < cnt) s2f = s2T[(size_t)b * NN + colr];
    csh[w][lane] = colr;
    wsh4[w][lane] = softmax4(s1f, s2f, lane, cnt, valr);

    // phase 2: z1[p][g] (same-wave LDS dependences only)
    {
        constexpr int STEP = (G == 32) ? 2 : 1;
        int sl = (G == 32) ? (lane >> 5) : 0;
        int g  = (G == 32) ? (lane & 31) : lane;
        float z0 = 0.f, z1 = 0.f, z2 = 0.f, z3 = 0.f;
        for (int jj = sl; jj < cnt; jj += STEP) {
            float xv = xT[((size_t)b * NN + csh[w][jj]) * G + g];
            float4 w4 = wsh4[w][jj];
            z0 += w4.x * xv; z1 += w4.y * xv; z2 += w4.z * xv; z3 += w4.w * xv;
        }
        if (G == 32) {
            z0 += __shfl_xor(z0, 32); z1 += __shfl_xor(z1, 32);
            z2 += __shfl_xor(z2, 32); z3 += __shfl_xor(z3, 32);
        }
        if (sl == 0) {
            z1sh[w][0][g] = z0; z1sh[w][1][g] = z1; z1sh[w][2][g] = z2; z1sh[w][3][g] = z3;
        }
    }

    // phase 3 (capture y at t2==lane for emit)
    float y0 = 0.f;
    for (int t2 = lane; t2 < PF; t2 += 64) {
        int p = t2 / F, f = t2 % F;
        const float* W0 = Wf + ((size_t)(p * 2)) * G * F + f;
        const float* W1 = W0 + G * F;
        float yv = bias[f];
#pragma unroll
        for (int gg = 0; gg < G; ++gg)
            yv += xish[w][gg] * W0[gg * F] + z1sh[w][p][gg] * W1[gg * F];
        if (t2 == lane) y0 = yv;
        float* d;
        if (layout == 0) d = dst + (size_t)node * PF + t2;
        else             d = dst + ((size_t)(b * PF + t2)) * NN + i;
        *d = yv;
    }

    if constexpr (ES >= 1) {
        emit_one<PF>(aE0, s1E0, s2E0, y0, lane, node);
        if constexpr (ES >= 2) emit_one<PF>(aE1, s1E1, s2E1, y0, lane, node);
    }
}

// ---------- GAT dual: y = gatA(xA) + gatB(xB); 4 independent waves ----------
template<int GA, int GB, int F, int ES>
__launch_bounds__(256)
__global__ void k_gat_dual(const float* __restrict__ xA, const float* __restrict__ xB,
                           const unsigned long long* __restrict__ segb,
                           const int* __restrict__ cols, const float* __restrict__ vals,
                           const float4* __restrict__ s1TA, const float4* __restrict__ s2TA,
                           const float4* __restrict__ s1TB, const float4* __restrict__ s2TB,
                           const float* __restrict__ WfA, const float* __restrict__ biasA,
                           const float* __restrict__ WfB, const float* __restrict__ biasB,
                           const float* __restrict__ aE0, float4* __restrict__ s1E0, float4* __restrict__ s2E0,
                           float* __restrict__ dst, int layout) {
    constexpr int PF = PP * F;
    __shared__ int    csh[4][64];
    __shared__ float4 wshA4[4][64];
    __shared__ float4 wshB4[4][64];
    __shared__ float  xishA[4][GA];
    __shared__ float  xishB[4][GB];
    __shared__ float  z1shA[4][PP][GA];
    __shared__ float  z1shB[4][PP][GB];

    int w = threadIdx.x >> 6;
    int lane = threadIdx.x & 63;
    int node = blockIdx.x * 4 + w;
    int b = node / NN, i = node % NN;

    if (lane < GA) xishA[w][lane] = xA[(size_t)node * GA + lane];
    if (lane < GB) xishB[w][lane] = xB[(size_t)node * GB + lane];
    int cnt, colr; float valr;
    adj_load(segb, cols, vals, node, lane, cnt, colr, valr);
    float4 s1fA = s1TA[node], s1fB = s1TB[node];
    float4 s2fA = make_float4(0.f, 0.f, 0.f, 0.f);
    float4 s2fB = make_float4(0.f, 0.f, 0.f, 0.f);
    if (lane < cnt) {
        s2fA = s2TA[(size_t)b * NN + colr];
        s2fB = s2TB[(size_t)b * NN + colr];
    }
    csh[w][lane] = colr;
    wshA4[w][lane] = softmax4(s1fA, s2fA, lane, cnt, valr);
    wshB4[w][lane] = softmax4(s1fB, s2fB, lane, cnt, valr);

    // phase 2 A
    {
        constexpr int STEP = (GA == 32) ? 2 : 1;
        int sl = (GA == 32) ? (lane >> 5) : 0;
        int g  = (GA == 32) ? (lane & 31) : lane;
        float z0 = 0.f, z1 = 0.f, z2 = 0.f, z3 = 0.f;
        for (int jj = sl; jj < cnt; jj += STEP) {
            float xv = xA[((size_t)b * NN + csh[w][jj]) * GA + g];
            float4 w4 = wshA4[w][jj];
            z0 += w4.x * xv; z1 += w4.y * xv; z2 += w4.z * xv; z3 += w4.w * xv;
        }
        if (GA == 32) {
            z0 += __shfl_xor(z0, 32); z1 += __shfl_xor(z1, 32);
            z2 += __shfl_xor(z2, 32); z3 += __shfl_xor(z3, 32);
        }
        if (sl == 0) {
            z1shA[w][0][g] = z0; z1shA[w][1][g] = z1; z1shA[w][2][g] = z2; z1shA[w][3][g] = z3;
        }
    }
    // phase 2 B
    {
        constexpr int STEP = (GB == 32) ? 2 : 1;
        int sl = (GB == 32) ? (lane >> 5) : 0;
        int g  = (GB == 32) ? (lane & 31) : lane;
        float z0 = 0.f, z1 = 0.f, z2 = 0.f, z3 = 0.f;
        for (int jj = sl; jj < cnt; jj += STEP) {
            float xv = xB[((size_t)b * NN + csh[w][jj]) * GB + g];
            float4 w4 = wshB4[w][jj];
            z0 += w4.x * xv; z1 += w4.y * xv; z2 += w4.z * xv; z3 += w4.w * xv;
        }
        if (GB == 32) {
            z0 += __shfl_xor(z0, 32); z1 += __shfl_xor(z1, 32);
            z2 += __shfl_xor(z2, 32); z3 += __shfl_xor(z3, 32);
        }
        if (sl == 0) {
            z1shB[w][0][g] = z0; z1shB[w][1][g] = z1; z1shB[w][2][g] = z2; z1shB[w][3][g] = z3;
        }
    }

    // phase 3: y = yA + yB
    float y0 = 0.f;
    for (int t2 = lane; t2 < PF; t2 += 64) {
        int p = t2 / F, f = t2 % F;
        const float* W0A = WfA + ((size_t)(p * 2)) * GA * F + f;
        const float* W1A = W0A + GA * F;
        const float* W0B = WfB + ((size_t)(p * 2)) * GB * F + f;
        const float* W1B = W0B + GB * F;
        float yv = biasA[f] + biasB[f];
#pragma unroll
        for (int gg = 0; gg < GA; ++gg)
            yv += xishA[w][gg] * W0A[gg * F] + z1shA[w][p][gg] * W1A[gg * F];
#pragma unroll
        for (int gg = 0; gg < GB; ++gg)
            yv += xishB[w][gg] * W0B[gg * F] + z1shB[w][p][gg] * W1B[gg * F];
        if (t2 == lane) y0 = yv;
        float* d;
        if (layout == 0) d = dst + (size_t)node * PF + t2;
        else             d = dst + ((size_t)(b * PF + t2)) * NN + i;
        *d = yv;
    }

    if constexpr (ES >= 1) {
        emit_one<PF>(aE0, s1E0, s2E0, y0, lane, node);
    }
}

// ---------- s1/s2 per node for f0 (dual a-set) ----------
template<int G>
__launch_bounds__(256)
__global__ void k_s1s2T(const float* __restrict__ xT,
                        const float* __restrict__ aA, float4* __restrict__ s1A, float4* __restrict__ s2A,
                        const float* __restrict__ aB, float4* __restrict__ s1B, float4* __restrict__ s2B) {
    int idx = blockIdx.x * 256 + threadIdx.x;
    if (idx >= BB * NN) return;
    const float* xr = xT + (size_t)idx * G;
    float xv[G];
#pragma unroll
    for (int g = 0; g < G; ++g) xv[g] = xr[g];
    {
        float a1[PP] = {0,0,0,0}, a2[PP] = {0,0,0,0};
#pragma unroll
        for (int g = 0; g < G; ++g) {
            float v = xv[g];
#pragma unroll
            for (int p = 0; p < PP; ++p) {
                a1[p] += aA[p * 2 * G + g] * v;
                a2[p] += aA[p * 2 * G + G + g] * v;
            }
        }
        s1A[idx] = make_float4(a1[0], a1[1], a1[2], a1[3]);
        s2A[idx] = make_float4(a2[0], a2[1], a2[2], a2[3]);
    }
    if (aB) {
        float a1[PP] = {0,0,0,0}, a2[PP] = {0,0,0,0};
#pragma unroll
        for (int g = 0; g < G; ++g) {
            float v = xv[g];
#pragma unroll
            for (int p = 0; p < PP; ++p) {
                a1[p] += aB[p * 2 * G + g] * v;
                a2[p] += aB[p * 2 * G + G + g] * v;
            }
        }
        s1B[idx] = make_float4(a1[0], a1[1], a1[2], a1[3]);
        s2B[idx] = make_float4(a2[0], a2[1], a2[2], a2[3]);
    }
}

// ---------- att = max over spatial ----------
__global__ void k_attmax(const float* __restrict__ d, float* __restrict__ att) {
    int wid = blockIdx.x;
    int lane = threadIdx.x;
    const float4* row = (const float4*)(d + (size_t)wid * NN);
    float m = -1e30f;
    for (int q = lane; q < 625; q += 64) {
        float4 f = row[q];
        m = fmaxf(m, fmaxf(fmaxf(f.x, f.y), fmaxf(f.z, f.w)));
    }
    for (int s = 32; s >= 1; s >>= 1) m = fmaxf(m, __shfl_xor(m, s));
    if (lane == 0) att[wid] = m;
}

// ---------- channel-attention MLP: one block per b ----------
__launch_bounds__(128)
__global__ void k_camlp(const float* __restrict__ att,
                        const float* __restrict__ w1, const float* __restrict__ b1,
                        const float* __restrict__ w2, const float* __restrict__ b2,
                        float* __restrict__ attf) {
    __shared__ float a[128];
    __shared__ float h[128];
    int b = blockIdx.x, t = threadIdx.x;
    a[t] = att[b * 128 + t];
    __syncthreads();
    float acc = b1[t];
    const float* wr = w1 + (size_t)t * 128;
    for (int k = 0; k < 128; ++k) acc += a[k] * wr[k];
    h[t] = fmaxf(acc, 0.f);
    __syncthreads();
    float acc2 = b2[t];
    const float* wr2 = w2 + (size_t)t * 128;
    for (int k = 0; k < 128; ++k) acc2 += h[k] * wr2[k];
    attf[b * 128 + t] = sigmoidf_(acc2);
}

// ---------- MLP ----------
__global__ void k_mlp1(const float* __restrict__ flat, const float* __restrict__ w,
                       const float* __restrict__ bias, float* __restrict__ out) {
    int wid = blockIdx.x;
    int lane = threadIdx.x;
    int o = wid % 512;
    int b = wid / 512;
    const float* fr = flat + b * NN;
    const float* wr = w + (size_t)o * NN;
    float acc = 0.f;
    for (int n = lane; n < NN; n += 64) acc += fr[n] * wr[n];
    for (int s = 32; s >= 1; s >>= 1) acc += __shfl_xor(acc, s);
    if (lane == 0) out[wid] = fmaxf(acc + bias[o], 0.0f);
}

__global__ void k_mlp2(const float* __restrict__ m, const float* __restrict__ w,
                       const float* __restrict__ bias, float* __restrict__ out) {
    int wid = blockIdx.x;
    int lane = threadIdx.x;
    int o = wid % 5;
    int b = wid / 5;
    const float* mr = m + b * 512;
    const float* wr = w + o * 512;
    float acc = 0.f;
    for (int k = lane; k < 512; k += 64) acc += mr[k] * wr[k];
    for (int s = 32; s >= 1; s >>= 1) acc += __shfl_xor(acc, s);
    if (lane == 0) out[wid] = 1.0f / (1.0f + expf(-(acc + bias[o])));
}

extern "C" void kernel_launch(void* const* d_in, const int* in_sizes, int n_in,
                              void* d_out, int out_size, void* d_ws, size_t ws_size,
                              hipStream_t stream) {
    const float* x       = (const float*)d_in[0];
    const float* Slist   = (const float*)d_in[1];
    const float* enc_w1  = (const float*)d_in[2];
    const float* enc_b1  = (const float*)d_in[3];
    const float* enc_w2  = (const float*)d_in[4];
    const float* enc_b2  = (const float*)d_in[5];
    const float* d0_a = (const float*)d_in[6];  const float* d0_W = (const float*)d_in[7];  const float* d0_b = (const float*)d_in[8];
    const float* d1_a = (const float*)d_in[9];  const float* d1_W = (const float*)d_in[10]; const float* d1_b = (const float*)d_in[11];
    const float* u0_a = (const float*)d_in[12]; const float* u0_W = (const float*)d_in[13]; const float* u0_b = (const float*)d_in[14];
    const float* u1_a = (const float*)d_in[15]; const float* u1_W = (const float*)d_in[16]; const float* u1_b = (const float*)d_in[17];
    const float* s0_a = (const float*)d_in[18]; const float* s0_W = (const float*)d_in[19]; const float* s0_b = (const float*)d_in[20];
    const float* s1_a = (const float*)d_in[21]; const float* s1_W = (const float*)d_in[22]; const float* s1_b = (const float*)d_in[23];
    const float* ca_w1 = (const float*)d_in[24]; const float* ca_b1 = (const float*)d_in[25];
    const float* ca_w2 = (const float*)d_in[26]; const float* ca_b2 = (const float*)d_in[27];
    const float* dec_w1 = (const float*)d_in[28]; const float* dec_b1 = (const float*)d_in[29];
    const float* dec_w2 = (const float*)d_in[30]; const float* dec_b2 = (const float*)d_in[31];
    const float* mlp_w1 = (const float*)d_in[32]; const float* mlp_b1 = (const float*)d_in[33];
    const float* mlp_w2 = (const float*)d_in[34]; const float* mlp_b2 = (const float*)d_in[35];
    float* out = (float*)d_out;

    // ---- workspace layout (f32 elements) ----
    float* ws = (float*)d_ws;
    size_t off = 0;
    auto alloc = [&](size_t n) { float* p = ws + off; off += n; return p; };
    float* h1    = alloc((size_t)BB * 32 * NN);
    float* xT_f0 = alloc((size_t)BB * NN * 32);
    float* xT_f1 = alloc((size_t)BB * NN * 64);
    float* xT_f2 = alloc((size_t)BB * NN * 32);
    float* xT_g1 = alloc((size_t)BB * NN * 64);
    float* g2    = alloc((size_t)BB * 128 * NN);
    unsigned long long* segb = (unsigned long long*)alloc((size_t)2 * BB * NN * 2);
    int*   cols = (int*)alloc((size_t)2 * BB * NN * SEGSTRIDE);
    float* valsb = alloc((size_t)2 * BB * NN * SEGSTRIDE);
    float4* s1_d0 = (float4*)alloc(4 * BB * NN); float4* s2_d0 = (float4*)alloc(4 * BB * NN);
    float4* s1_s0 = (float4*)alloc(4 * BB * NN); float4* s2_s0 = (float4*)alloc(4 * BB * NN);
    float4* s1_d1 = (float4*)alloc(4 * BB * NN); float4* s2_d1 = (float4*)alloc(4 * BB * NN);
    float4* s1_sc1= (float4*)alloc(4 * BB * NN); float4* s2_sc1= (float4*)alloc(4 * BB * NN);
    float4* s1_u0 = (float4*)alloc(4 * BB * NN); float4* s2_u0 = (float4*)alloc(4 * BB * NN);
    float4* s1_u1 = (float4*)alloc(4 * BB * NN); float4* s2_u1 = (float4*)alloc(4 * BB * NN);
    float* att   = alloc(BB * 128);
    float* attf  = alloc(BB * 128);
    float* dec1o = alloc((size_t)BB * 32 * NN);
    float* dec2o = alloc((size_t)BB * NN);
    float* mbuf  = alloc((size_t)BB * 512);
    float* wre1  = alloc(32 * 3 * 9);
    float* wre2  = alloc(32 * 32 * 9);
    float* wre3  = alloc(32 * 128 * 9);
    float* wre4  = alloc(1 * 32 * 9);
    float* partial = alloc((size_t)8 * BB * 32 * NN);
    (void)ws_size;

    const int T = 256;
    const unsigned long long* segb0 = segb;
    const unsigned long long* segb1 = segb + (size_t)BB * NN;
    const int* col0 = cols;
    const int* col1 = cols + (size_t)BB * NN * SEGSTRIDE;
    const float* val0 = valsb;
    const float* val1 = valsb + (size_t)BB * NN * SEGSTRIDE;

    // 0. weight repack
    k_repack<<<cdiv(32 * 128 * 9, T), T, 0, stream>>>(enc_w1, enc_w2, dec_w1, dec_w2,
                                                      wre1, wre2, wre3, wre4);
    // 1. enc conv1 (3->32), fused sigmoid
    k_conv_enc1<<<BB * 4 * PXB2, 256, 0, stream>>>(x, wre1, enc_b1, h1);
    // 2. enc conv2 (32->32)
    k_conv_part<8><<<BB * 4 * 4 * PXB2, 256, 0, stream>>>(h1, wre2, nullptr, partial,
                                                          32, 32, 4, 4, 8, 0.0f);
    k_conv_reduce<<<cdiv(BB * 32 * NN, T), T, 0, stream>>>(partial, enc_b2, nullptr, xT_f0, 32, 4);
    // 3. segmented adjacency
    k_build_adj<<<cdiv(2 * BB * NN * SEGS, 4), 256, 0, stream>>>(Slist, segb, cols, valsb);
    // 4. s1/s2 for f0 (d0 + s0 sets)
    k_s1s2T<32><<<cdiv(BB * NN, 256), 256, 0, stream>>>(xT_f0, d0_a, s1_d0, s2_d0,
                                                        s0_a, s1_s0, s2_s0);
    // 5. f1 = gat(f0, S0, down0); emit s1s2 for d1 and sc1
    k_gat_wave<32,16,2><<<BB * NN / 4, 256, 0, stream>>>(
        xT_f0, segb0, col0, val0, s1_d0, s2_d0, d0_W, d0_b,
        d1_a, s1_d1, s2_d1, s1_a, s1_sc1, s2_sc1, xT_f1, 0);
    // 6. f2 = gat(f1, S1, down1); emit s1s2 for u0
    k_gat_wave<64,8,1><<<BB * NN / 4, 256, 0, stream>>>(
        xT_f1, segb1, col1, val1, s1_d1, s2_d1, d1_W, d1_b,
        u0_a, s1_u0, s2_u0, nullptr, nullptr, nullptr, xT_f2, 0);
    // 7. g1 = gat(f2, S1, up0) + gat(f1, S1, sc1); emit s1s2 for u1
    k_gat_dual<32,64,16,1><<<BB * NN / 4, 256, 0, stream>>>(
        xT_f2, xT_f1, segb1, col1, val1,
        s1_u0, s2_u0, s1_sc1, s2_sc1,
        u0_W, u0_b, s1_W, s1_b,
        u1_a, s1_u1, s2_u1, xT_g1, 0);
    // 8. g2 = gat(g1, S0, up1) + gat(f0, S0, sc0)  (channel-major)
    k_gat_dual<64,32,32,0><<<BB * NN / 4, 256, 0, stream>>>(
        xT_g1, xT_f0, segb0, col0, val0,
        s1_u1, s2_u1, s1_s0, s2_s0,
        u1_W, u1_b, s0_W, s0_b,
        nullptr, nullptr, nullptr, g2, 1);
    // 9. channel attention
    k_attmax<<<BB * 128, 64, 0, stream>>>(g2, att);
    k_camlp<<<BB, 128, 0, stream>>>(att, ca_w1, ca_b1, ca_w2, ca_b2, attf);
    // 10. decoder convs (pad -999; att-scale fused)
    k_conv_part<8><<<BB * 8 * 4 * PXB2, 256, 0, stream>>>(g2, wre3, attf, partial,
                                                          128, 32, 4, 8, 16, -999.0f);
    k_conv_reduce<<<cdiv(BB * 32 * NN, T), T, 0, stream>>>(partial, dec_b1, dec1o, nullptr, 32, 8);
    k_conv_part<1><<<BB * 4 * 1 * PXB2, 256, 0, stream>>>(dec1o, wre4, nullptr, partial,
                                                          32, 1, 1, 4, 8, -999.0f);
    k_conv_reduce<<<cdiv(BB * 1 * NN, T), T, 0, stream>>>(partial, dec_b2, dec2o, nullptr, 1, 4);
    // 11. MLP head
    k_mlp1<<<BB * 512, 64, 0, stream>>>(dec2o, mlp_w1, mlp_b1, mbuf);
    k_mlp2<<<BB * 5, 64, 0, stream>>>(mbuf, mlp_w2, mlp_b2, out);
}

// Round 8
// 317.015 us; speedup vs baseline: 1.1298x; 1.1298x over previous
//
#include <hip/hip_runtime.h>
#include <hip/hip_bf16.h>
#include <math.h>

// ---- problem constants ----
#define BB 2
#define HH 50
#define WW 50
#define NN 2500            // H*W
#define PP 4
#define LRELU_SLOPE 0.2f
#define ZTOL 1e-9f
#define PXB2 10            // ceil(2500/256)
#define SEGS 5             // adjacency segments per row
#define SEGCAP 32          // slots per segment
#define SEGSTRIDE (SEGS * SEGCAP)   // 160

static inline int cdiv(int a, int b) { return (a + b - 1) / b; }

__device__ __forceinline__ float sigmoidf_(float v) { return 1.0f / (1.0f + expf(-v)); }

// ---------- weight repack: w[oc][ic][tap] -> wre[(ic*9+tap)*OC + oc] ----------
__global__ void k_repack(const float* __restrict__ e1, const float* __restrict__ e2,
                         const float* __restrict__ dd1, const float* __restrict__ dd2,
                         float* __restrict__ r1, float* __restrict__ r2,
                         float* __restrict__ r3, float* __restrict__ r4) {
    int i = blockIdx.x * blockDim.x + threadIdx.x;
    if (i < 32 * 3 * 9)  { int oc = i / 27;  int rem = i % 27;  int ic = rem / 9; int tp = rem % 9; r1[(ic * 9 + tp) * 32 + oc] = e1[i]; }
    if (i < 32 * 32 * 9) { int oc = i / 288; int rem = i % 288; int ic = rem / 9; int tp = rem % 9; r2[(ic * 9 + tp) * 32 + oc] = e2[i]; }
    if (i < 32 * 128 * 9){ int oc = i / 1152;int rem = i % 1152;int ic = rem / 9; int tp = rem % 9; r3[(ic * 9 + tp) * 32 + oc] = dd1[i]; }
    if (i < 1 * 32 * 9)  { int oc = 0;       int rem = i;       int ic = rem / 9; int tp = rem % 9; r4[(ic * 9 + tp) * 1  + oc] = dd2[i]; }
}

// ---------- enc conv1 (3->32) with fused sigmoid ----------
__launch_bounds__(256)
__global__ void k_conv_enc1(const float* __restrict__ x, const float* __restrict__ wre,
                            const float* __restrict__ bias, float* __restrict__ out) {
    int bx = blockIdx.x;
    int pxb = bx % PXB2;
    int ocg = (bx / PXB2) % 4;
    int b = bx / (PXB2 * 4);
    int px = pxb * 256 + threadIdx.x;
    bool valid = px < NN;
    int xx0 = px % WW, yy0 = px / WW;
    float acc[8];
#pragma unroll
    for (int o = 0; o < 8; ++o) acc[o] = 0.f;
    for (int ic = 0; ic < 3; ++ic) {
        const float* ip = x + ((size_t)(b * 3 + ic)) * NN;
        float v[9];
#pragma unroll
        for (int ky = 0; ky < 3; ++ky) {
            int yy = yy0 + ky - 1;
#pragma unroll
            for (int kx = 0; kx < 3; ++kx) {
                int xx = xx0 + kx - 1;
                bool ok = valid && yy >= 0 && yy < HH && xx >= 0 && xx < WW;
                v[ky * 3 + kx] = ok ? sigmoidf_(ip[yy * WW + xx]) : 0.f;
            }
        }
        const float* wp = wre + (size_t)ic * 9 * 32 + ocg * 8;
#pragma unroll
        for (int tp = 0; tp < 9; ++tp) {
            float vv = v[tp];
#pragma unroll
            for (int o = 0; o < 8; ++o) acc[o] += wp[tp * 32 + o] * vv;
        }
    }
    if (valid) {
#pragma unroll
        for (int o = 0; o < 8; ++o) {
            int oc = ocg * 8 + o;
            out[((size_t)(b * 32 + oc)) * NN + px] = fmaxf(acc[o] + bias[oc], 0.f);
        }
    }
}

// ---------- generic chunked conv3x3 partials ----------
template<int OCT>
__launch_bounds__(256)
__global__ void k_conv_part(const float* __restrict__ in, const float* __restrict__ wre,
                            const float* __restrict__ attscale,
                            float* __restrict__ part, int Cin, int OC, int nocg,
                            int nchunks, int icchunk, float padval) {
    int bx = blockIdx.x;
    int pxb = bx % PXB2; bx /= PXB2;
    int ocg = bx % nocg; bx /= nocg;
    int chunk = bx % nchunks;
    int b = bx / nchunks;
    int px = pxb * 256 + threadIdx.x;
    bool valid = px < NN;
    int xx0 = px % WW, yy0 = px / WW;

    float acc[OCT];
#pragma unroll
    for (int o = 0; o < OCT; ++o) acc[o] = 0.f;

    int ic0 = chunk * icchunk;
    int ic1 = ic0 + icchunk; if (ic1 > Cin) ic1 = Cin;

    for (int ic = ic0; ic < ic1; ++ic) {
        const float* ip = in + ((size_t)(b * Cin + ic)) * NN;
        float attv = attscale ? attscale[b * Cin + ic] : 1.f;
        float v[9];
#pragma unroll
        for (int ky = 0; ky < 3; ++ky) {
            int yy = yy0 + ky - 1;
#pragma unroll
            for (int kx = 0; kx < 3; ++kx) {
                int xx = xx0 + kx - 1;
                bool ok = valid && yy >= 0 && yy < HH && xx >= 0 && xx < WW;
                v[ky * 3 + kx] = ok ? ip[yy * WW + xx] * attv : padval;
            }
        }
        const float* wp = wre + (size_t)ic * 9 * OC + ocg * OCT;
#pragma unroll
        for (int tp = 0; tp < 9; ++tp) {
            float vv = v[tp];
#pragma unroll
            for (int o = 0; o < OCT; ++o) acc[o] += wp[tp * OC + o] * vv;
        }
    }
    if (valid) {
#pragma unroll
        for (int o = 0; o < OCT; ++o)
            part[(((size_t)chunk * BB + b) * OC + ocg * OCT + o) * NN + px] = acc[o];
    }
}

// ---------- reduce chunks + bias + relu; dual-layout write ----------
__global__ void k_conv_reduce(const float* __restrict__ part, const float* __restrict__ bias,
                              float* __restrict__ out, float* __restrict__ xTout,
                              int OCr, int nchunks) {
    int idx = blockIdx.x * blockDim.x + threadIdx.x;
    int total = BB * OCr * NN;
    if (idx >= total) return;
    int px = idx % NN;
    int oc = (idx / NN) % OCr;
    int b = idx / (NN * OCr);
    float s = bias[oc];
    for (int c = 0; c < nchunks; ++c)
        s += part[(((size_t)c * BB + b) * OCr + oc) * NN + px];
    s = fmaxf(s, 0.f);
    if (out)   out[((size_t)(b * OCr + oc)) * NN + px] = s;
    if (xTout) xTout[((size_t)b * NN + px) * OCr + oc] = s;
}

// ---------- segmented adjacency build ----------
__launch_bounds__(256)
__global__ void k_build_adj(const float* __restrict__ S,
                            unsigned long long* __restrict__ segb,
                            int* __restrict__ cols, float* __restrict__ vals) {
    int wg = blockIdx.x * 4 + (threadIdx.x >> 6);
    int lane = threadIdx.x & 63;
    int row = wg / SEGS;
    int seg = wg % SEGS;
    if (row >= 2 * BB * NN) return;
    int i = row % NN;
    int b = (row / NN) % BB;
    int s = row / (NN * BB);
    const float4* Srow = (const float4*)(S + (((size_t)(b * 2 + s)) * NN + i) * NN);
    int qb = seg * 125;

    float4 f1 = Srow[qb + lane];
    bool l2ok = lane < 61;
    float4 f2 = make_float4(0.f, 0.f, 0.f, 0.f);
    if (l2ok) f2 = Srow[qb + 64 + lane];

    unsigned long long below = (lane == 63) ? 0x7fffffffffffffffull
                                            : ((1ull << lane) - 1ull);
    unsigned long long a0 = __ballot(fabsf(f1.x) > ZTOL);
    unsigned long long a1 = __ballot(fabsf(f1.y) > ZTOL);
    unsigned long long a2 = __ballot(fabsf(f1.z) > ZTOL);
    unsigned long long a3 = __ballot(fabsf(f1.w) > ZTOL);
    unsigned long long c0 = __ballot(l2ok && fabsf(f2.x) > ZTOL);
    unsigned long long c1 = __ballot(l2ok && fabsf(f2.y) > ZTOL);
    unsigned long long c2 = __ballot(l2ok && fabsf(f2.z) > ZTOL);
    unsigned long long c3 = __ballot(l2ok && fabsf(f2.w) > ZTOL);

    int n1 = __popcll(a0) + __popcll(a1) + __popcll(a2) + __popcll(a3);
    int total = n1 + __popcll(c0) + __popcll(c1) + __popcll(c2) + __popcll(c3);

    size_t base = (size_t)row * SEGSTRIDE + seg * SEGCAP;
    {
        int idx = __popcll(a0 & below) + __popcll(a1 & below) +
                  __popcll(a2 & below) + __popcll(a3 & below);
        int j0 = (qb + lane) * 4;
        if ((a0 >> lane) & 1) { if (idx < SEGCAP) { cols[base + idx] = j0 + 0; vals[base + idx] = f1.x; } ++idx; }
        if ((a1 >> lane) & 1) { if (idx < SEGCAP) { cols[base + idx] = j0 + 1; vals[base + idx] = f1.y; } ++idx; }
        if ((a2 >> lane) & 1) { if (idx < SEGCAP) { cols[base + idx] = j0 + 2; vals[base + idx] = f1.z; } ++idx; }
        if ((a3 >> lane) & 1) { if (idx < SEGCAP) { cols[base + idx] = j0 + 3; vals[base + idx] = f1.w; } ++idx; }
    }
    {
        int idx = n1 + __popcll(c0 & below) + __popcll(c1 & below) +
                       __popcll(c2 & below) + __popcll(c3 & below);
        int j1 = (qb + 64 + lane) * 4;
        if ((c0 >> lane) & 1) { if (idx < SEGCAP) { cols[base + idx] = j1 + 0; vals[base + idx] = f2.x; } ++idx; }
        if ((c1 >> lane) & 1) { if (idx < SEGCAP) { cols[base + idx] = j1 + 1; vals[base + idx] = f2.y; } ++idx; }
        if ((c2 >> lane) & 1) { if (idx < SEGCAP) { cols[base + idx] = j1 + 2; vals[base + idx] = f2.z; } ++idx; }
        if ((c3 >> lane) & 1) { if (idx < SEGCAP) { cols[base + idx] = j1 + 3; vals[base + idx] = f2.w; } ++idx; }
    }
    if (lane == 0) {
        int t = total > SEGCAP ? SEGCAP : total;
        ((unsigned char*)segb)[(size_t)row * 8 + seg] = (unsigned char)t;
    }
}

// ---------- adjacency reader ----------
__device__ __forceinline__ void adj_load(const unsigned long long* __restrict__ segb,
                                         const int* __restrict__ cols,
                                         const float* __restrict__ vals,
                                         int node, int lane,
                                         int& cnt, int& colr, float& valr) {
    unsigned long long sb = segb[node];
    int c0 = (int)(sb & 0xff), c1 = (int)((sb >> 8) & 0xff), c2 = (int)((sb >> 16) & 0xff),
        c3 = (int)((sb >> 24) & 0xff), c4 = (int)((sb >> 32) & 0xff);
    int cum1 = c0, cum2 = cum1 + c1, cum3 = cum2 + c2, cum4 = cum3 + c3;
    cnt = cum4 + c4; if (cnt > 64) cnt = 64;
    int seg = 0, basec = 0;
    if (lane >= cum1) { seg = 1; basec = cum1; }
    if (lane >= cum2) { seg = 2; basec = cum2; }
    if (lane >= cum3) { seg = 3; basec = cum3; }
    if (lane >= cum4) { seg = 4; basec = cum4; }
    colr = 0; valr = 0.f;
    if (lane < cnt) {
        size_t sl = (size_t)node * SEGSTRIDE + seg * SEGCAP + (lane - basec);
        colr = cols[sl];
        valr = vals[sl];
    }
}

// ---------- per-head masked softmax * S ----------
__device__ __forceinline__ float4 softmax4(float4 s1f, float4 s2f, int lane, int cnt, float valr) {
    float e[PP] = { s1f.x + s2f.x, s1f.y + s2f.y, s1f.z + s2f.z, s1f.w + s2f.w };
    float w[PP];
#pragma unroll
    for (int p = 0; p < PP; ++p) {
        float v = e[p];
        v = (v < 0.f) ? LRELU_SLOPE * v : v;
        v = (lane < cnt) ? v : -1e30f;
        float mx = v;
#pragma unroll
        for (int m = 32; m >= 1; m >>= 1) mx = fmaxf(mx, __shfl_xor(mx, m));
        float ex = (lane < cnt) ? expf(v - mx) : 0.f;
        float sm = ex;
#pragma unroll
        for (int m = 32; m >= 1; m >>= 1) sm += __shfl_xor(sm, m);
        w[p] = (cnt > 0) ? ex / sm * valr : 0.f;
    }
    return make_float4(w[0], w[1], w[2], w[3]);
}

// ---------- emit s1/s2 (lane holds y element `lane`, PF<=64) ----------
template<int PF>
__device__ __forceinline__ void emit_one(const float* __restrict__ a,
                                         float4* __restrict__ s1E, float4* __restrict__ s2E,
                                         float yl, int lane, int node) {
    float r1[PP], r2[PP];
#pragma unroll
    for (int p = 0; p < PP; ++p) {
        float v1 = (lane < PF) ? a[p * 2 * PF + lane] * yl : 0.f;
        float v2 = (lane < PF) ? a[p * 2 * PF + PF + lane] * yl : 0.f;
#pragma unroll
        for (int m = 32; m >= 1; m >>= 1) { v1 += __shfl_xor(v1, m); v2 += __shfl_xor(v2, m); }
        r1[p] = v1; r2[p] = v2;
    }
    if (lane == 0) {
        s1E[node] = make_float4(r1[0], r1[1], r1[2], r1[3]);
        s2E[node] = make_float4(r2[0], r2[1], r2[2], r2[3]);
    }
}

// ---------- sparse part: softmax + neighbor gather -> z1 (and z1B if DUAL) ----------
template<int G, int DUAL>
__launch_bounds__(256)
__global__ void k_zgather(const float* __restrict__ xT,
                          const unsigned long long* __restrict__ segb,
                          const int* __restrict__ cols, const float* __restrict__ vals,
                          const float4* __restrict__ s1A, const float4* __restrict__ s2A,
                          float* __restrict__ z1A,
                          const float4* __restrict__ s1B, const float4* __restrict__ s2B,
                          float* __restrict__ z1B) {
    __shared__ int    csh[4][64];
    __shared__ float4 wAsh[4][64];
    __shared__ float4 wBsh[DUAL ? 4 : 1][DUAL ? 64 : 1];

    int w = threadIdx.x >> 6;
    int lane = threadIdx.x & 63;
    int node = blockIdx.x * 4 + w;          // grid exact: 5000/4
    int b = node / NN;

    int cnt, colr; float valr;
    adj_load(segb, cols, vals, node, lane, cnt, colr, valr);
    float4 s2fA = make_float4(0.f, 0.f, 0.f, 0.f);
    float4 s2fB = make_float4(0.f, 0.f, 0.f, 0.f);
    if (lane < cnt) {
        s2fA = s2A[(size_t)b * NN + colr];
        if (DUAL) s2fB = s2B[(size_t)b * NN + colr];
    }
    csh[w][lane] = colr;
    wAsh[w][lane] = softmax4(s1A[node], s2fA, lane, cnt, valr);
    if (DUAL) wBsh[w][lane] = softmax4(s1B[node], s2fB, lane, cnt, valr);

    constexpr int STEP = (G == 32) ? 2 : 1;
    int sl = (G == 32) ? (lane >> 5) : 0;
    int g  = (G == 32) ? (lane & 31) : lane;
    float zA[PP] = {0.f, 0.f, 0.f, 0.f};
    float zB[PP] = {0.f, 0.f, 0.f, 0.f};
    for (int jj = sl; jj < cnt; jj += STEP) {
        float xv = xT[((size_t)b * NN + csh[w][jj]) * G + g];
        float4 wa = wAsh[w][jj];
        zA[0] += wa.x * xv; zA[1] += wa.y * xv; zA[2] += wa.z * xv; zA[3] += wa.w * xv;
        if (DUAL) {
            float4 wb = wBsh[w][jj];
            zB[0] += wb.x * xv; zB[1] += wb.y * xv; zB[2] += wb.z * xv; zB[3] += wb.w * xv;
        }
    }
    if (G == 32) {
#pragma unroll
        for (int p = 0; p < PP; ++p) {
            zA[p] += __shfl_xor(zA[p], 32);
            if (DUAL) zB[p] += __shfl_xor(zB[p], 32);
        }
    }
    if (sl == 0) {
#pragma unroll
        for (int p = 0; p < PP; ++p) {
            z1A[((size_t)node * PP + p) * G + g] = zA[p];
            if (DUAL) z1B[((size_t)node * PP + p) * G + g] = zB[p];
        }
    }
}

// ---------- dense part: y = bias + x*W0 + z1*W1 (+ dual B side), LDS-tiled ----------
template<int GA, int GB, int F, int DUAL, int LAY, int ES>
__launch_bounds__(256)
__global__ void k_dense(const float* __restrict__ xA, const float* __restrict__ z1A,
                        const float* __restrict__ WfA, const float* __restrict__ biasA,
                        const float* __restrict__ xB, const float* __restrict__ z1B,
                        const float* __restrict__ WfB, const float* __restrict__ biasB,
                        const float* __restrict__ aE0, float4* __restrict__ s1E0, float4* __restrict__ s2E0,
                        const float* __restrict__ aE1, float4* __restrict__ s1E1, float4* __restrict__ s2E1,
                        float* __restrict__ dst) {
    constexpr int PF = PP * F;
    constexpr int NPB = 256 / F;
    constexpr int XA = GA + 1, ZA = PP * GA + 1;
    constexpr int XB = GB + 1, ZB = PP * GB + 1;
    constexpr int WSZ = 2 * GA * F + (DUAL ? 2 * GB * F : 0);
    __shared__ float xAsh[NPB * XA];
    __shared__ float z1Ash[NPB * ZA];
    __shared__ float xBsh[DUAL ? NPB * XB : 1];
    __shared__ float z1Bsh[DUAL ? NPB * ZB : 1];
    __shared__ float Wsh[WSZ];
    __shared__ float ysh[ES ? NPB * (PF + 1) : 1];

    int tid = threadIdx.x;
    int node0 = blockIdx.x * NPB;

    // stage x / z1 (global reads fully coalesced; LDS padded)
    for (int idx = tid; idx < NPB * GA; idx += 256) {
        int nl2 = idx / GA, g = idx % GA;
        int nn = node0 + nl2;
        xAsh[nl2 * XA + g] = (nn < BB * NN) ? xA[(size_t)nn * GA + g] : 0.f;
    }
    for (int idx = tid; idx < NPB * PP * GA; idx += 256) {
        int nl2 = idx / (PP * GA), r = idx % (PP * GA);
        int nn = node0 + nl2;
        z1Ash[nl2 * ZA + r] = (nn < BB * NN) ? z1A[(size_t)nn * PP * GA + r] : 0.f;
    }
    if (DUAL) {
        for (int idx = tid; idx < NPB * GB; idx += 256) {
            int nl2 = idx / GB, g = idx % GB;
            int nn = node0 + nl2;
            xBsh[nl2 * XB + g] = (nn < BB * NN) ? xB[(size_t)nn * GB + g] : 0.f;
        }
        for (int idx = tid; idx < NPB * PP * GB; idx += 256) {
            int nl2 = idx / (PP * GB), r = idx % (PP * GB);
            int nn = node0 + nl2;
            z1Bsh[nl2 * ZB + r] = (nn < BB * NN) ? z1B[(size_t)nn * PP * GB + r] : 0.f;
        }
    }

    int fi, nl;
    if (LAY == 1) { nl = tid % NPB; fi = tid / NPB; }
    else          { fi = tid % F;   nl = tid / F;   }
    int node = node0 + nl;
    int b = node / NN, i = node % NN;
    bool ok = node < BB * NN;
    float bsum = biasA[fi] + (DUAL ? biasB[fi] : 0.f);

    for (int p = 0; p < PP; ++p) {
        __syncthreads();
        for (int idx = tid; idx < 2 * GA * F; idx += 256)
            Wsh[idx] = WfA[(size_t)p * 2 * GA * F + idx];
        if (DUAL)
            for (int idx = tid; idx < 2 * GB * F; idx += 256)
                Wsh[2 * GA * F + idx] = WfB[(size_t)p * 2 * GB * F + idx];
        __syncthreads();

        float y = bsum;
        const float* W0 = Wsh;
        const float* W1 = Wsh + GA * F;
#pragma unroll
        for (int g = 0; g < GA; ++g)
            y += xAsh[nl * XA + g] * W0[g * F + fi] +
                 z1Ash[nl * ZA + p * GA + g] * W1[g * F + fi];
        if (DUAL) {
            const float* V0 = Wsh + 2 * GA * F;
            const float* V1 = V0 + GB * F;
#pragma unroll
            for (int g = 0; g < GB; ++g)
                y += xBsh[nl * XB + g] * V0[g * F + fi] +
                     z1Bsh[nl * ZB + p * GB + g] * V1[g * F + fi];
        }
        int oc = p * F + fi;
        if (ok) {
            if (LAY == 1) dst[((size_t)(b * PF + oc)) * NN + i] = y;
            else          dst[(size_t)node * PF + oc] = y;
        }
        if (ES) ysh[nl * (PF + 1) + oc] = y;
    }

    if (ES) {
        __syncthreads();
        int w = tid >> 6, lane = tid & 63;
        for (int nl2 = w; nl2 < NPB; nl2 += 4) {
            int nn = node0 + nl2;
            if (nn >= BB * NN) break;
            float yl = (lane < PF) ? ysh[nl2 * (PF + 1) + lane] : 0.f;
            emit_one<PF>(aE0, s1E0, s2E0, yl, lane, nn);
            if (ES >= 2) emit_one<PF>(aE1, s1E1, s2E1, yl, lane, nn);
        }
    }
}

// ---------- s1/s2 per node for f0 (dual a-set) ----------
template<int G>
__launch_bounds__(256)
__global__ void k_s1s2T(const float* __restrict__ xT,
                        const float* __restrict__ aA, float4* __restrict__ s1A, float4* __restrict__ s2A,
                        const float* __restrict__ aB, float4* __restrict__ s1B, float4* __restrict__ s2B) {
    int idx = blockIdx.x * 256 + threadIdx.x;
    if (idx >= BB * NN) return;
    const float* xr = xT + (size_t)idx * G;
    float xv[G];
#pragma unroll
    for (int g = 0; g < G; ++g) xv[g] = xr[g];
    {
        float a1[PP] = {0,0,0,0}, a2[PP] = {0,0,0,0};
#pragma unroll
        for (int g = 0; g < G; ++g) {
            float v = xv[g];
#pragma unroll
            for (int p = 0; p < PP; ++p) {
                a1[p] += aA[p * 2 * G + g] * v;
                a2[p] += aA[p * 2 * G + G + g] * v;
            }
        }
        s1A[idx] = make_float4(a1[0], a1[1], a1[2], a1[3]);
        s2A[idx] = make_float4(a2[0], a2[1], a2[2], a2[3]);
    }
    if (aB) {
        float a1[PP] = {0,0,0,0}, a2[PP] = {0,0,0,0};
#pragma unroll
        for (int g = 0; g < G; ++g) {
            float v = xv[g];
#pragma unroll
            for (int p = 0; p < PP; ++p) {
                a1[p] += aB[p * 2 * G + g] * v;
                a2[p] += aB[p * 2 * G + G + g] * v;
            }
        }
        s1B[idx] = make_float4(a1[0], a1[1], a1[2], a1[3]);
        s2B[idx] = make_float4(a2[0], a2[1], a2[2], a2[3]);
    }
}

// ---------- att = max over spatial ----------
__global__ void k_attmax(const float* __restrict__ d, float* __restrict__ att) {
    int wid = blockIdx.x;
    int lane = threadIdx.x;
    const float4* row = (const float4*)(d + (size_t)wid * NN);
    float m = -1e30f;
    for (int q = lane; q < 625; q += 64) {
        float4 f = row[q];
        m = fmaxf(m, fmaxf(fmaxf(f.x, f.y), fmaxf(f.z, f.w)));
    }
    for (int s = 32; s >= 1; s >>= 1) m = fmaxf(m, __shfl_xor(m, s));
    if (lane == 0) att[wid] = m;
}

// ---------- channel-attention MLP ----------
__launch_bounds__(128)
__global__ void k_camlp(const float* __restrict__ att,
                        const float* __restrict__ w1, const float* __restrict__ b1,
                        const float* __restrict__ w2, const float* __restrict__ b2,
                        float* __restrict__ attf) {
    __shared__ float a[128];
    __shared__ float h[128];
    int b = blockIdx.x, t = threadIdx.x;
    a[t] = att[b * 128 + t];
    __syncthreads();
    float acc = b1[t];
    const float* wr = w1 + (size_t)t * 128;
    for (int k = 0; k < 128; ++k) acc += a[k] * wr[k];
    h[t] = fmaxf(acc, 0.f);
    __syncthreads();
    float acc2 = b2[t];
    const float* wr2 = w2 + (size_t)t * 128;
    for (int k = 0; k < 128; ++k) acc2 += h[k] * wr2[k];
    attf[b * 128 + t] = sigmoidf_(acc2);
}

// ---------- MLP ----------
__global__ void k_mlp1(const float* __restrict__ flat, const float* __restrict__ w,
                       const float* __restrict__ bias, float* __restrict__ out) {
    int wid = blockIdx.x;
    int lane = threadIdx.x;
    int o = wid % 512;
    int b = wid / 512;
    const float* fr = flat + b * NN;
    const float* wr = w + (size_t)o * NN;
    float acc = 0.f;
    for (int n = lane; n < NN; n += 64) acc += fr[n] * wr[n];
    for (int s = 32; s >= 1; s >>= 1) acc += __shfl_xor(acc, s);
    if (lane == 0) out[wid] = fmaxf(acc + bias[o], 0.0f);
}

__global__ void k_mlp2(const float* __restrict__ m, const float* __restrict__ w,
                       const float* __restrict__ bias, float* __restrict__ out) {
    int wid = blockIdx.x;
    int lane = threadIdx.x;
    int o = wid % 5;
    int b = wid / 5;
    const float* mr = m + b * 512;
    const float* wr = w + o * 512;
    float acc = 0.f;
    for (int k = lane; k < 512; k += 64) acc += mr[k] * wr[k];
    for (int s = 32; s >= 1; s >>= 1) acc += __shfl_xor(acc, s);
    if (lane == 0) out[wid] = 1.0f / (1.0f + expf(-(acc + bias[o])));
}

extern "C" void kernel_launch(void* const* d_in, const int* in_sizes, int n_in,
                              void* d_out, int out_size, void* d_ws, size_t ws_size,
                              hipStream_t stream) {
    const float* x       = (const float*)d_in[0];
    const float* Slist   = (const float*)d_in[1];
    const float* enc_w1  = (const float*)d_in[2];
    const float* enc_b1  = (const float*)d_in[3];
    const float* enc_w2  = (const float*)d_in[4];
    const float* enc_b2  = (const float*)d_in[5];
    const float* d0_a = (const float*)d_in[6];  const float* d0_W = (const float*)d_in[7];  const float* d0_b = (const float*)d_in[8];
    const float* d1_a = (const float*)d_in[9];  const float* d1_W = (const float*)d_in[10]; const float* d1_b = (const float*)d_in[11];
    const float* u0_a = (const float*)d_in[12]; const float* u0_W = (const float*)d_in[13]; const float* u0_b = (const float*)d_in[14];
    const float* u1_a = (const float*)d_in[15]; const float* u1_W = (const float*)d_in[16]; const float* u1_b = (const float*)d_in[17];
    const float* s0_a = (const float*)d_in[18]; const float* s0_W = (const float*)d_in[19]; const float* s0_b = (const float*)d_in[20];
    const float* s1_a = (const float*)d_in[21]; const float* s1_W = (const float*)d_in[22]; const float* s1_b = (const float*)d_in[23];
    const float* ca_w1 = (const float*)d_in[24]; const float* ca_b1 = (const float*)d_in[25];
    const float* ca_w2 = (const float*)d_in[26]; const float* ca_b2 = (const float*)d_in[27];
    const float* dec_w1 = (const float*)d_in[28]; const float* dec_b1 = (const float*)d_in[29];
    const float* dec_w2 = (const float*)d_in[30]; const float* dec_b2 = (const float*)d_in[31];
    const float* mlp_w1 = (const float*)d_in[32]; const float* mlp_b1 = (const float*)d_in[33];
    const float* mlp_w2 = (const float*)d_in[34]; const float* mlp_b2 = (const float*)d_in[35];
    float* out = (float*)d_out;

    // ---- workspace layout (f32 elements) ----
    float* ws = (float*)d_ws;
    size_t off = 0;
    auto alloc = [&](size_t n) { float* p = ws + off; off += n; return p; };
    float* h1    = alloc((size_t)BB * 32 * NN);
    float* xT_f0 = alloc((size_t)BB * NN * 32);
    float* xT_f1 = alloc((size_t)BB * NN * 64);
    float* xT_f2 = alloc((size_t)BB * NN * 32);
    float* xT_g1 = alloc((size_t)BB * NN * 64);
    float* g2    = alloc((size_t)BB * 128 * NN);
    unsigned long long* segb = (unsigned long long*)alloc((size_t)2 * BB * NN * 2);
    int*   cols = (int*)alloc((size_t)2 * BB * NN * SEGSTRIDE);
    float* valsb = alloc((size_t)2 * BB * NN * SEGSTRIDE);
    float4* s1_d0 = (float4*)alloc(4 * BB * NN); float4* s2_d0 = (float4*)alloc(4 * BB * NN);
    float4* s1_s0 = (float4*)alloc(4 * BB * NN); float4* s2_s0 = (float4*)alloc(4 * BB * NN);
    float4* s1_d1 = (float4*)alloc(4 * BB * NN); float4* s2_d1 = (float4*)alloc(4 * BB * NN);
    float4* s1_sc1= (float4*)alloc(4 * BB * NN); float4* s2_sc1= (float4*)alloc(4 * BB * NN);
    float4* s1_u0 = (float4*)alloc(4 * BB * NN); float4* s2_u0 = (float4*)alloc(4 * BB * NN);
    float4* s1_u1 = (float4*)alloc(4 * BB * NN); float4* s2_u1 = (float4*)alloc(4 * BB * NN);
    float* z1_d0  = alloc((size_t)BB * NN * PP * 32);
    float* z1_s0  = alloc((size_t)BB * NN * PP * 32);
    float* z1_d1  = alloc((size_t)BB * NN * PP * 64);
    float* z1_sc1 = alloc((size_t)BB * NN * PP * 64);
    float* z1_u0  = alloc((size_t)BB * NN * PP * 32);
    float* z1_u1  = alloc((size_t)BB * NN * PP * 64);
    float* att   = alloc(BB * 128);
    float* attf  = alloc(BB * 128);
    float* dec1o = alloc((size_t)BB * 32 * NN);
    float* dec2o = alloc((size_t)BB * NN);
    float* mbuf  = alloc((size_t)BB * 512);
    float* wre1  = alloc(32 * 3 * 9);
    float* wre2  = alloc(32 * 32 * 9);
    float* wre3  = alloc(32 * 128 * 9);
    float* wre4  = alloc(1 * 32 * 9);
    float* partial = alloc((size_t)8 * BB * 32 * NN);
    (void)ws_size;

    const int T = 256;
    const int NNODE = BB * NN;          // 5000
    const unsigned long long* segb0 = segb;
    const unsigned long long* segb1 = segb + (size_t)NNODE;
    const int* col0 = cols;
    const int* col1 = cols + (size_t)NNODE * SEGSTRIDE;
    const float* val0 = valsb;
    const float* val1 = valsb + (size_t)NNODE * SEGSTRIDE;

    // 0. weight repack + encoder
    k_repack<<<cdiv(32 * 128 * 9, T), T, 0, stream>>>(enc_w1, enc_w2, dec_w1, dec_w2,
                                                      wre1, wre2, wre3, wre4);
    k_conv_enc1<<<BB * 4 * PXB2, 256, 0, stream>>>(x, wre1, enc_b1, h1);
    k_conv_part<8><<<BB * 4 * 4 * PXB2, 256, 0, stream>>>(h1, wre2, nullptr, partial,
                                                          32, 32, 4, 4, 8, 0.0f);
    k_conv_reduce<<<cdiv(BB * 32 * NN, T), T, 0, stream>>>(partial, enc_b2, nullptr, xT_f0, 32, 4);
    // 1. adjacency
    k_build_adj<<<cdiv(2 * NNODE * SEGS, 4), 256, 0, stream>>>(Slist, segb, cols, valsb);
    // 2. s1/s2 on f0 for d0 + s0
    k_s1s2T<32><<<cdiv(NNODE, 256), 256, 0, stream>>>(xT_f0, d0_a, s1_d0, s2_d0,
                                                      s0_a, s1_s0, s2_s0);
    // 3. sparse {d0,s0} on (f0,S0)
    k_zgather<32,1><<<NNODE / 4, 256, 0, stream>>>(xT_f0, segb0, col0, val0,
                                                   s1_d0, s2_d0, z1_d0,
                                                   s1_s0, s2_s0, z1_s0);
    // 4. dense f1 = proj(f0, z1_d0); emit s1s2 for d1 (PF=64) and sc1 (PF=64)
    k_dense<32,32,16,0,0,2><<<cdiv(NNODE, 16), 256, 0, stream>>>(
        xT_f0, z1_d0, d0_W, d0_b, nullptr, nullptr, nullptr, nullptr,
        d1_a, s1_d1, s2_d1, s1_a, s1_sc1, s2_sc1, xT_f1);
    // 5. sparse {d1,sc1} on (f1,S1)
    k_zgather<64,1><<<NNODE / 4, 256, 0, stream>>>(xT_f1, segb1, col1, val1,
                                                   s1_d1, s2_d1, z1_d1,
                                                   s1_sc1, s2_sc1, z1_sc1);
    // 6. dense f2 = proj(f1, z1_d1); emit s1s2 for u0 (PF=32)
    k_dense<64,32,8,0,0,1><<<cdiv(NNODE, 32), 256, 0, stream>>>(
        xT_f1, z1_d1, d1_W, d1_b, nullptr, nullptr, nullptr, nullptr,
        u0_a, s1_u0, s2_u0, nullptr, nullptr, nullptr, xT_f2);
    // 7. sparse {u0} on (f2,S1)
    k_zgather<32,0><<<NNODE / 4, 256, 0, stream>>>(xT_f2, segb1, col1, val1,
                                                   s1_u0, s2_u0, z1_u0,
                                                   nullptr, nullptr, nullptr);
    // 8. dense g1 = proj(f2, z1_u0) + proj(f1, z1_sc1); emit s1s2 for u1 (PF=64)
    k_dense<32,64,16,1,0,1><<<cdiv(NNODE, 16), 256, 0, stream>>>(
        xT_f2, z1_u0, u0_W, u0_b, xT_f1, z1_sc1, s1_W, s1_b,
        u1_a, s1_u1, s2_u1, nullptr, nullptr, nullptr, xT_g1);
    // 9. sparse {u1} on (g1,S0)
    k_zgather<64,0><<<NNODE / 4, 256, 0, stream>>>(xT_g1, segb0, col0, val0,
                                                   s1_u1, s2_u1, z1_u1,
                                                   nullptr, nullptr, nullptr);
    // 10. dense g2 = proj(g1, z1_u1) + proj(f0, z1_s0)  (channel-major)
    k_dense<64,32,32,1,1,0><<<cdiv(NNODE, 8), 256, 0, stream>>>(
        xT_g1, z1_u1, u1_W, u1_b, xT_f0, z1_s0, s0_W, s0_b,
        nullptr, nullptr, nullptr, nullptr, nullptr, nullptr, g2);
    // 11. channel attention (scale fused into dec conv1)
    k_attmax<<<BB * 128, 64, 0, stream>>>(g2, att);
    k_camlp<<<BB, 128, 0, stream>>>(att, ca_w1, ca_b1, ca_w2, ca_b2, attf);
    // 12. decoder convs (pad -999)
    k_conv_part<8><<<BB * 8 * 4 * PXB2, 256, 0, stream>>>(g2, wre3, attf, partial,
                                                          128, 32, 4, 8, 16, -999.0f);
    k_conv_reduce<<<cdiv(BB * 32 * NN, T), T, 0, stream>>>(partial, dec_b1, dec1o, nullptr, 32, 8);
    k_conv_part<1><<<BB * 4 * 1 * PXB2, 256, 0, stream>>>(dec1o, wre4, nullptr, partial,
                                                          32, 1, 1, 4, 8, -999.0f);
    k_conv_reduce<<<cdiv(BB * 1 * NN, T), T, 0, stream>>>(partial, dec_b2, dec2o, nullptr, 1, 4);
    // 13. MLP head
    k_mlp1<<<BB * 512, 64, 0, stream>>>(dec2o, mlp_w1, mlp_b1, mbuf);
    k_mlp2<<<BB * 5, 64, 0, stream>>>(mbuf, mlp_w2, mlp_b2, out);
}

// Round 9
// 306.121 us; speedup vs baseline: 1.1700x; 1.0356x over previous
//
#include <hip/hip_runtime.h>
#include <hip/hip_bf16.h>
#include <math.h>

// ---- problem constants ----
#define BB 2
#define HH 50
#define WW 50
#define NN 2500            // H*W
#define PP 4
#define LRELU_SLOPE 0.2f
#define ZTOL 1e-9f
#define PXB2 10            // ceil(2500/256)
#define SEGS 5             // adjacency segments per row
#define SEGCAP 32          // slots per segment
#define SEGSTRIDE (SEGS * SEGCAP)   // 160

static inline int cdiv(int a, int b) { return (a + b - 1) / b; }

__device__ __forceinline__ float sigmoidf_(float v) { return 1.0f / (1.0f + expf(-v)); }

// ---------- weight repack: w[oc][ic][tap] -> wre[(ic*9+tap)*OC + oc] ----------
__global__ void k_repack(const float* __restrict__ e1, const float* __restrict__ e2,
                         const float* __restrict__ dd1, const float* __restrict__ dd2,
                         float* __restrict__ r1, float* __restrict__ r2,
                         float* __restrict__ r3, float* __restrict__ r4) {
    int i = blockIdx.x * blockDim.x + threadIdx.x;
    if (i < 32 * 3 * 9)  { int oc = i / 27;  int rem = i % 27;  int ic = rem / 9; int tp = rem % 9; r1[(ic * 9 + tp) * 32 + oc] = e1[i]; }
    if (i < 32 * 32 * 9) { int oc = i / 288; int rem = i % 288; int ic = rem / 9; int tp = rem % 9; r2[(ic * 9 + tp) * 32 + oc] = e2[i]; }
    if (i < 32 * 128 * 9){ int oc = i / 1152;int rem = i % 1152;int ic = rem / 9; int tp = rem % 9; r3[(ic * 9 + tp) * 32 + oc] = dd1[i]; }
    if (i < 1 * 32 * 9)  { int oc = 0;       int rem = i;       int ic = rem / 9; int tp = rem % 9; r4[(ic * 9 + tp) * 1  + oc] = dd2[i]; }
}

// ---------- enc conv1 (3->32) with fused sigmoid ----------
__launch_bounds__(256)
__global__ void k_conv_enc1(const float* __restrict__ x, const float* __restrict__ wre,
                            const float* __restrict__ bias, float* __restrict__ out) {
    int bx = blockIdx.x;
    int pxb = bx % PXB2;
    int ocg = (bx / PXB2) % 4;
    int b = bx / (PXB2 * 4);
    int px = pxb * 256 + threadIdx.x;
    bool valid = px < NN;
    int xx0 = px % WW, yy0 = px / WW;
    float acc[8];
#pragma unroll
    for (int o = 0; o < 8; ++o) acc[o] = 0.f;
    for (int ic = 0; ic < 3; ++ic) {
        const float* ip = x + ((size_t)(b * 3 + ic)) * NN;
        float v[9];
#pragma unroll
        for (int ky = 0; ky < 3; ++ky) {
            int yy = yy0 + ky - 1;
#pragma unroll
            for (int kx = 0; kx < 3; ++kx) {
                int xx = xx0 + kx - 1;
                bool ok = valid && yy >= 0 && yy < HH && xx >= 0 && xx < WW;
                v[ky * 3 + kx] = ok ? sigmoidf_(ip[yy * WW + xx]) : 0.f;
            }
        }
        const float* wp = wre + (size_t)ic * 9 * 32 + ocg * 8;
#pragma unroll
        for (int tp = 0; tp < 9; ++tp) {
            float vv = v[tp];
#pragma unroll
            for (int o = 0; o < 8; ++o) acc[o] += wp[tp * 32 + o] * vv;
        }
    }
    if (valid) {
#pragma unroll
        for (int o = 0; o < 8; ++o) {
            int oc = ocg * 8 + o;
            out[((size_t)(b * 32 + oc)) * NN + px] = fmaxf(acc[o] + bias[oc], 0.f);
        }
    }
}

// ---------- generic chunked conv3x3 partials ----------
template<int OCT>
__launch_bounds__(256)
__global__ void k_conv_part(const float* __restrict__ in, const float* __restrict__ wre,
                            const float* __restrict__ attscale,
                            float* __restrict__ part, int Cin, int OC, int nocg,
                            int nchunks, int icchunk, float padval) {
    int bx = blockIdx.x;
    int pxb = bx % PXB2; bx /= PXB2;
    int ocg = bx % nocg; bx /= nocg;
    int chunk = bx % nchunks;
    int b = bx / nchunks;
    int px = pxb * 256 + threadIdx.x;
    bool valid = px < NN;
    int xx0 = px % WW, yy0 = px / WW;

    float acc[OCT];
#pragma unroll
    for (int o = 0; o < OCT; ++o) acc[o] = 0.f;

    int ic0 = chunk * icchunk;
    int ic1 = ic0 + icchunk; if (ic1 > Cin) ic1 = Cin;

    for (int ic = ic0; ic < ic1; ++ic) {
        const float* ip = in + ((size_t)(b * Cin + ic)) * NN;
        float attv = attscale ? attscale[b * Cin + ic] : 1.f;
        float v[9];
#pragma unroll
        for (int ky = 0; ky < 3; ++ky) {
            int yy = yy0 + ky - 1;
#pragma unroll
            for (int kx = 0; kx < 3; ++kx) {
                int xx = xx0 + kx - 1;
                bool ok = valid && yy >= 0 && yy < HH && xx >= 0 && xx < WW;
                v[ky * 3 + kx] = ok ? ip[yy * WW + xx] * attv : padval;
            }
        }
        const float* wp = wre + (size_t)ic * 9 * OC + ocg * OCT;
#pragma unroll
        for (int tp = 0; tp < 9; ++tp) {
            float vv = v[tp];
#pragma unroll
            for (int o = 0; o < OCT; ++o) acc[o] += wp[tp * OC + o] * vv;
        }
    }
    if (valid) {
#pragma unroll
        for (int o = 0; o < OCT; ++o)
            part[(((size_t)chunk * BB + b) * OC + ocg * OCT + o) * NN + px] = acc[o];
    }
}

// ---------- reduce chunks + bias + relu; dual-layout write ----------
__global__ void k_conv_reduce(const float* __restrict__ part, const float* __restrict__ bias,
                              float* __restrict__ out, float* __restrict__ xTout,
                              int OCr, int nchunks) {
    int idx = blockIdx.x * blockDim.x + threadIdx.x;
    int total = BB * OCr * NN;
    if (idx >= total) return;
    int px = idx % NN;
    int oc = (idx / NN) % OCr;
    int b = idx / (NN * OCr);
    float s = bias[oc];
    for (int c = 0; c < nchunks; ++c)
        s += part[(((size_t)c * BB + b) * OCr + oc) * NN + px];
    s = fmaxf(s, 0.f);
    if (out)   out[((size_t)(b * OCr + oc)) * NN + px] = s;
    if (xTout) xTout[((size_t)b * NN + px) * OCr + oc] = s;
}

// ---------- dec conv2 (32->1) single pass ----------
__launch_bounds__(256)
__global__ void k_conv_dec2(const float* __restrict__ in, const float* __restrict__ wre,
                            const float* __restrict__ bias, float* __restrict__ out) {
    int pxb = blockIdx.x % PXB2;
    int b = blockIdx.x / PXB2;
    int px = pxb * 256 + threadIdx.x;
    bool valid = px < NN;
    int xx0 = px % WW, yy0 = px / WW;
    float acc = 0.f;
    for (int ic = 0; ic < 32; ++ic) {
        const float* ip = in + ((size_t)(b * 32 + ic)) * NN;
#pragma unroll
        for (int ky = 0; ky < 3; ++ky) {
            int yy = yy0 + ky - 1;
#pragma unroll
            for (int kx = 0; kx < 3; ++kx) {
                int xx = xx0 + kx - 1;
                bool ok = valid && yy >= 0 && yy < HH && xx >= 0 && xx < WW;
                float v = ok ? ip[yy * WW + xx] : -999.0f;
                acc += v * wre[ic * 9 + ky * 3 + kx];
            }
        }
    }
    if (valid) out[(size_t)b * NN + px] = fmaxf(acc + bias[0], 0.f);
}

// ---------- segmented adjacency build ----------
__launch_bounds__(256)
__global__ void k_build_adj(const float* __restrict__ S,
                            unsigned long long* __restrict__ segb,
                            int* __restrict__ cols, float* __restrict__ vals) {
    int wg = blockIdx.x * 4 + (threadIdx.x >> 6);
    int lane = threadIdx.x & 63;
    int row = wg / SEGS;
    int seg = wg % SEGS;
    if (row >= 2 * BB * NN) return;
    int i = row % NN;
    int b = (row / NN) % BB;
    int s = row / (NN * BB);
    const float4* Srow = (const float4*)(S + (((size_t)(b * 2 + s)) * NN + i) * NN);
    int qb = seg * 125;

    float4 f1 = Srow[qb + lane];
    bool l2ok = lane < 61;
    float4 f2 = make_float4(0.f, 0.f, 0.f, 0.f);
    if (l2ok) f2 = Srow[qb + 64 + lane];

    unsigned long long below = (lane == 63) ? 0x7fffffffffffffffull
                                            : ((1ull << lane) - 1ull);
    unsigned long long a0 = __ballot(fabsf(f1.x) > ZTOL);
    unsigned long long a1 = __ballot(fabsf(f1.y) > ZTOL);
    unsigned long long a2 = __ballot(fabsf(f1.z) > ZTOL);
    unsigned long long a3 = __ballot(fabsf(f1.w) > ZTOL);
    unsigned long long c0 = __ballot(l2ok && fabsf(f2.x) > ZTOL);
    unsigned long long c1 = __ballot(l2ok && fabsf(f2.y) > ZTOL);
    unsigned long long c2 = __ballot(l2ok && fabsf(f2.z) > ZTOL);
    unsigned long long c3 = __ballot(l2ok && fabsf(f2.w) > ZTOL);

    int n1 = __popcll(a0) + __popcll(a1) + __popcll(a2) + __popcll(a3);
    int total = n1 + __popcll(c0) + __popcll(c1) + __popcll(c2) + __popcll(c3);

    size_t base = (size_t)row * SEGSTRIDE + seg * SEGCAP;
    {
        int idx = __popcll(a0 & below) + __popcll(a1 & below) +
                  __popcll(a2 & below) + __popcll(a3 & below);
        int j0 = (qb + lane) * 4;
        if ((a0 >> lane) & 1) { if (idx < SEGCAP) { cols[base + idx] = j0 + 0; vals[base + idx] = f1.x; } ++idx; }
        if ((a1 >> lane) & 1) { if (idx < SEGCAP) { cols[base + idx] = j0 + 1; vals[base + idx] = f1.y; } ++idx; }
        if ((a2 >> lane) & 1) { if (idx < SEGCAP) { cols[base + idx] = j0 + 2; vals[base + idx] = f1.z; } ++idx; }
        if ((a3 >> lane) & 1) { if (idx < SEGCAP) { cols[base + idx] = j0 + 3; vals[base + idx] = f1.w; } ++idx; }
    }
    {
        int idx = n1 + __popcll(c0 & below) + __popcll(c1 & below) +
                       __popcll(c2 & below) + __popcll(c3 & below);
        int j1 = (qb + 64 + lane) * 4;
        if ((c0 >> lane) & 1) { if (idx < SEGCAP) { cols[base + idx] = j1 + 0; vals[base + idx] = f2.x; } ++idx; }
        if ((c1 >> lane) & 1) { if (idx < SEGCAP) { cols[base + idx] = j1 + 1; vals[base + idx] = f2.y; } ++idx; }
        if ((c2 >> lane) & 1) { if (idx < SEGCAP) { cols[base + idx] = j1 + 2; vals[base + idx] = f2.z; } ++idx; }
        if ((c3 >> lane) & 1) { if (idx < SEGCAP) { cols[base + idx] = j1 + 3; vals[base + idx] = f2.w; } ++idx; }
    }
    if (lane == 0) {
        int t = total > SEGCAP ? SEGCAP : total;
        ((unsigned char*)segb)[(size_t)row * 8 + seg] = (unsigned char)t;
    }
}

// ---------- adjacency reader ----------
__device__ __forceinline__ void adj_load(const unsigned long long* __restrict__ segb,
                                         const int* __restrict__ cols,
                                         const float* __restrict__ vals,
                                         int node, int lane,
                                         int& cnt, int& colr, float& valr) {
    unsigned long long sb = segb[node];
    int c0 = (int)(sb & 0xff), c1 = (int)((sb >> 8) & 0xff), c2 = (int)((sb >> 16) & 0xff),
        c3 = (int)((sb >> 24) & 0xff), c4 = (int)((sb >> 32) & 0xff);
    int cum1 = c0, cum2 = cum1 + c1, cum3 = cum2 + c2, cum4 = cum3 + c3;
    cnt = cum4 + c4; if (cnt > 64) cnt = 64;
    int seg = 0, basec = 0;
    if (lane >= cum1) { seg = 1; basec = cum1; }
    if (lane >= cum2) { seg = 2; basec = cum2; }
    if (lane >= cum3) { seg = 3; basec = cum3; }
    if (lane >= cum4) { seg = 4; basec = cum4; }
    colr = 0; valr = 0.f;
    if (lane < cnt) {
        size_t sl = (size_t)node * SEGSTRIDE + seg * SEGCAP + (lane - basec);
        colr = cols[sl];
        valr = vals[sl];
    }
}

// ---------- per-head masked softmax * S ----------
__device__ __forceinline__ float4 softmax4(float4 s1f, float4 s2f, int lane, int cnt, float valr) {
    float e[PP] = { s1f.x + s2f.x, s1f.y + s2f.y, s1f.z + s2f.z, s1f.w + s2f.w };
    float w[PP];
#pragma unroll
    for (int p = 0; p < PP; ++p) {
        float v = e[p];
        v = (v < 0.f) ? LRELU_SLOPE * v : v;
        v = (lane < cnt) ? v : -1e30f;
        float mx = v;
#pragma unroll
        for (int m = 32; m >= 1; m >>= 1) mx = fmaxf(mx, __shfl_xor(mx, m));
        float ex = (lane < cnt) ? expf(v - mx) : 0.f;
        float sm = ex;
#pragma unroll
        for (int m = 32; m >= 1; m >>= 1) sm += __shfl_xor(sm, m);
        w[p] = (cnt > 0) ? ex / sm * valr : 0.f;
    }
    return make_float4(w[0], w[1], w[2], w[3]);
}

// ---------- emit s1/s2 (lane holds y element `lane`, PF<=64) ----------
template<int PF>
__device__ __forceinline__ void emit_one(const float* __restrict__ a,
                                         float4* __restrict__ s1E, float4* __restrict__ s2E,
                                         float yl, int lane, int node) {
    float r1[PP], r2[PP];
#pragma unroll
    for (int p = 0; p < PP; ++p) {
        float v1 = (lane < PF) ? a[p * 2 * PF + lane] * yl : 0.f;
        float v2 = (lane < PF) ? a[p * 2 * PF + PF + lane] * yl : 0.f;
#pragma unroll
        for (int m = 32; m >= 1; m >>= 1) { v1 += __shfl_xor(v1, m); v2 += __shfl_xor(v2, m); }
        r1[p] = v1; r2[p] = v2;
    }
    if (lane == 0) {
        s1E[node] = make_float4(r1[0], r1[1], r1[2], r1[3]);
        s2E[node] = make_float4(r2[0], r2[1], r2[2], r2[3]);
    }
}

// ---------- sparse part: softmax + neighbor gather -> z1 (and z1B if DUAL) ----------
template<int G, int DUAL>
__launch_bounds__(256)
__global__ void k_zgather(const float* __restrict__ xT,
                          const unsigned long long* __restrict__ segb,
                          const int* __restrict__ cols, const float* __restrict__ vals,
                          const float4* __restrict__ s1A, const float4* __restrict__ s2A,
                          float* __restrict__ z1A,
                          const float4* __restrict__ s1B, const float4* __restrict__ s2B,
                          float* __restrict__ z1B) {
    __shared__ int    csh[4][64];
    __shared__ float4 wAsh[4][64];
    __shared__ float4 wBsh[DUAL ? 4 : 1][DUAL ? 64 : 1];

    int w = threadIdx.x >> 6;
    int lane = threadIdx.x & 63;
    int node = blockIdx.x * 4 + w;
    int b = node / NN;

    int cnt, colr; float valr;
    adj_load(segb, cols, vals, node, lane, cnt, colr, valr);
    float4 s2fA = make_float4(0.f, 0.f, 0.f, 0.f);
    float4 s2fB = make_float4(0.f, 0.f, 0.f, 0.f);
    if (lane < cnt) {
        s2fA = s2A[(size_t)b * NN + colr];
        if (DUAL) s2fB = s2B[(size_t)b * NN + colr];
    }
    csh[w][lane] = colr;
    wAsh[w][lane] = softmax4(s1A[node], s2fA, lane, cnt, valr);
    if (DUAL) wBsh[w][lane] = softmax4(s1B[node], s2fB, lane, cnt, valr);

    constexpr int STEP = (G == 32) ? 2 : 1;
    int sl = (G == 32) ? (lane >> 5) : 0;
    int g  = (G == 32) ? (lane & 31) : lane;
    float zA[PP] = {0.f, 0.f, 0.f, 0.f};
    float zB[PP] = {0.f, 0.f, 0.f, 0.f};
    for (int jj = sl; jj < cnt; jj += STEP) {
        float xv = xT[((size_t)b * NN + csh[w][jj]) * G + g];
        float4 wa = wAsh[w][jj];
        zA[0] += wa.x * xv; zA[1] += wa.y * xv; zA[2] += wa.z * xv; zA[3] += wa.w * xv;
        if (DUAL) {
            float4 wb = wBsh[w][jj];
            zB[0] += wb.x * xv; zB[1] += wb.y * xv; zB[2] += wb.z * xv; zB[3] += wb.w * xv;
        }
    }
    if (G == 32) {
#pragma unroll
        for (int p = 0; p < PP; ++p) {
            zA[p] += __shfl_xor(zA[p], 32);
            if (DUAL) zB[p] += __shfl_xor(zB[p], 32);
        }
    }
    if (sl == 0) {
#pragma unroll
        for (int p = 0; p < PP; ++p) {
            z1A[((size_t)node * PP + p) * G + g] = zA[p];
            if (DUAL) z1B[((size_t)node * PP + p) * G + g] = zB[p];
        }
    }
}

// ---------- dense part: y = bias + x*W0 + z1*W1 (+ dual B side), LDS-tiled ----------
template<int GA, int GB, int F, int DUAL, int LAY, int ES>
__launch_bounds__(256)
__global__ void k_dense(const float* __restrict__ xA, const float* __restrict__ z1A,
                        const float* __restrict__ WfA, const float* __restrict__ biasA,
                        const float* __restrict__ xB, const float* __restrict__ z1B,
                        const float* __restrict__ WfB, const float* __restrict__ biasB,
                        const float* __restrict__ aE0, float4* __restrict__ s1E0, float4* __restrict__ s2E0,
                        const float* __restrict__ aE1, float4* __restrict__ s1E1, float4* __restrict__ s2E1,
                        float* __restrict__ dst) {
    constexpr int PF = PP * F;
    constexpr int NPB = 256 / F;
    constexpr int XA = GA + 1, ZA = PP * GA + 1;
    constexpr int XB = GB + 1, ZB = PP * GB + 1;
    constexpr int WSZ = 2 * GA * F + (DUAL ? 2 * GB * F : 0);
    __shared__ float xAsh[NPB * XA];
    __shared__ float z1Ash[NPB * ZA];
    __shared__ float xBsh[DUAL ? NPB * XB : 1];
    __shared__ float z1Bsh[DUAL ? NPB * ZB : 1];
    __shared__ float Wsh[WSZ];
    __shared__ float ysh[ES ? NPB * (PF + 1) : 1];

    int tid = threadIdx.x;
    int node0 = blockIdx.x * NPB;

    for (int idx = tid; idx < NPB * GA; idx += 256) {
        int nl2 = idx / GA, g = idx % GA;
        int nn = node0 + nl2;
        xAsh[nl2 * XA + g] = (nn < BB * NN) ? xA[(size_t)nn * GA + g] : 0.f;
    }
    for (int idx = tid; idx < NPB * PP * GA; idx += 256) {
        int nl2 = idx / (PP * GA), r = idx % (PP * GA);
        int nn = node0 + nl2;
        z1Ash[nl2 * ZA + r] = (nn < BB * NN) ? z1A[(size_t)nn * PP * GA + r] : 0.f;
    }
    if (DUAL) {
        for (int idx = tid; idx < NPB * GB; idx += 256) {
            int nl2 = idx / GB, g = idx % GB;
            int nn = node0 + nl2;
            xBsh[nl2 * XB + g] = (nn < BB * NN) ? xB[(size_t)nn * GB + g] : 0.f;
        }
        for (int idx = tid; idx < NPB * PP * GB; idx += 256) {
            int nl2 = idx / (PP * GB), r = idx % (PP * GB);
            int nn = node0 + nl2;
            z1Bsh[nl2 * ZB + r] = (nn < BB * NN) ? z1B[(size_t)nn * PP * GB + r] : 0.f;
        }
    }

    int fi, nl;
    if (LAY == 1) { nl = tid % NPB; fi = tid / NPB; }
    else          { fi = tid % F;   nl = tid / F;   }
    int node = node0 + nl;
    int b = node / NN, i = node % NN;
    bool ok = node < BB * NN;
    float bsum = biasA[fi] + (DUAL ? biasB[fi] : 0.f);

    for (int p = 0; p < PP; ++p) {
        __syncthreads();
        for (int idx = tid; idx < 2 * GA * F; idx += 256)
            Wsh[idx] = WfA[(size_t)p * 2 * GA * F + idx];
        if (DUAL)
            for (int idx = tid; idx < 2 * GB * F; idx += 256)
                Wsh[2 * GA * F + idx] = WfB[(size_t)p * 2 * GB * F + idx];
        __syncthreads();

        float y = bsum;
        const float* W0 = Wsh;
        const float* W1 = Wsh + GA * F;
#pragma unroll
        for (int g = 0; g < GA; ++g)
            y += xAsh[nl * XA + g] * W0[g * F + fi] +
                 z1Ash[nl * ZA + p * GA + g] * W1[g * F + fi];
        if (DUAL) {
            const float* V0 = Wsh + 2 * GA * F;
            const float* V1 = V0 + GB * F;
#pragma unroll
            for (int g = 0; g < GB; ++g)
                y += xBsh[nl * XB + g] * V0[g * F + fi] +
                     z1Bsh[nl * ZB + p * GB + g] * V1[g * F + fi];
        }
        int oc = p * F + fi;
        if (ok) {
            if (LAY == 1) dst[((size_t)(b * PF + oc)) * NN + i] = y;
            else          dst[(size_t)node * PF + oc] = y;
        }
        if (ES) ysh[nl * (PF + 1) + oc] = y;
    }

    if (ES) {
        __syncthreads();
        int w = tid >> 6, lane = tid & 63;
        for (int nl2 = w; nl2 < NPB; nl2 += 4) {
            int nn = node0 + nl2;
            if (nn >= BB * NN) break;
            float yl = (lane < PF) ? ysh[nl2 * (PF + 1) + lane] : 0.f;
            emit_one<PF>(aE0, s1E0, s2E0, yl, lane, nn);
            if (ES >= 2) emit_one<PF>(aE1, s1E1, s2E1, yl, lane, nn);
        }
    }
}

// ---------- dense with head-split across blocks (ES=0 only) ----------
template<int GA, int GB, int F, int DUAL, int LAY>
__launch_bounds__(256)
__global__ void k_dense_psplit(const float* __restrict__ xA, const float* __restrict__ z1A,
                               const float* __restrict__ WfA, const float* __restrict__ biasA,
                               const float* __restrict__ xB, const float* __restrict__ z1B,
                               const float* __restrict__ WfB, const float* __restrict__ biasB,
                               float* __restrict__ dst) {
    constexpr int PF = PP * F;
    constexpr int NPB = 256 / F;
    constexpr int XA = GA + 1, ZA = GA + 1;
    constexpr int XB = GB + 1, ZB = GB + 1;
    __shared__ float xAsh[NPB * XA];
    __shared__ float z1Ash[NPB * ZA];
    __shared__ float xBsh[DUAL ? NPB * XB : 1];
    __shared__ float z1Bsh[DUAL ? NPB * ZB : 1];
    __shared__ float Wsh[2 * GA * F + (DUAL ? 2 * GB * F : 0)];

    int tid = threadIdx.x;
    int p = blockIdx.x % PP;
    int node0 = (blockIdx.x / PP) * NPB;

    for (int idx = tid; idx < NPB * GA; idx += 256) {
        int nl2 = idx / GA, g = idx % GA;
        int nn = node0 + nl2;
        xAsh[nl2 * XA + g] = (nn < BB * NN) ? xA[(size_t)nn * GA + g] : 0.f;
        z1Ash[nl2 * ZA + g] = (nn < BB * NN) ? z1A[((size_t)nn * PP + p) * GA + g] : 0.f;
    }
    if (DUAL) {
        for (int idx = tid; idx < NPB * GB; idx += 256) {
            int nl2 = idx / GB, g = idx % GB;
            int nn = node0 + nl2;
            xBsh[nl2 * XB + g] = (nn < BB * NN) ? xB[(size_t)nn * GB + g] : 0.f;
            z1Bsh[nl2 * ZB + g] = (nn < BB * NN) ? z1B[((size_t)nn * PP + p) * GB + g] : 0.f;
        }
    }
    for (int idx = tid; idx < 2 * GA * F; idx += 256)
        Wsh[idx] = WfA[(size_t)p * 2 * GA * F + idx];
    if (DUAL)
        for (int idx = tid; idx < 2 * GB * F; idx += 256)
            Wsh[2 * GA * F + idx] = WfB[(size_t)p * 2 * GB * F + idx];
    __syncthreads();

    int fi, nl;
    if (LAY == 1) { nl = tid % NPB; fi = tid / NPB; }
    else          { fi = tid % F;   nl = tid / F;   }
    int node = node0 + nl;
    int b = node / NN, i = node % NN;
    if (node >= BB * NN) return;

    float y = biasA[fi] + (DUAL ? biasB[fi] : 0.f);
    const float* W0 = Wsh;
    const float* W1 = Wsh + GA * F;
#pragma unroll
    for (int g = 0; g < GA; ++g)
        y += xAsh[nl * XA + g] * W0[g * F + fi] + z1Ash[nl * ZA + g] * W1[g * F + fi];
    if (DUAL) {
        const float* V0 = Wsh + 2 * GA * F;
        const float* V1 = V0 + GB * F;
#pragma unroll
        for (int g = 0; g < GB; ++g)
            y += xBsh[nl * XB + g] * V0[g * F + fi] + z1Bsh[nl * ZB + g] * V1[g * F + fi];
    }
    int oc = p * F + fi;
    if (LAY == 1) dst[((size_t)(b * PF + oc)) * NN + i] = y;
    else          dst[(size_t)node * PF + oc] = y;
}

// ---------- s1/s2 for f0: coalesced LDS-staged block kernel ----------
template<int G>
__launch_bounds__(256)
__global__ void k_s1s2T(const float* __restrict__ xT,
                        const float* __restrict__ aA, float4* __restrict__ s1A, float4* __restrict__ s2A,
                        const float* __restrict__ aB, float4* __restrict__ s1B, float4* __restrict__ s2B) {
    constexpr int NPB = 16;
    __shared__ float xsh[NPB][G + 1];
    __shared__ float ash[2][2][PP][G];     // [set][which][p][g]
    __shared__ float ysh[NPB][17];         // 16 outputs, padded

    int tid = threadIdx.x;
    int node0 = blockIdx.x * NPB;

    for (int idx = tid; idx < PP * 2 * G; idx += 256) {
        int p = idx / (2 * G), r = idx % (2 * G);
        int which = r / G, g = r % G;
        ash[0][which][p][g] = aA[idx];
        if (aB) ash[1][which][p][g] = aB[idx];
    }
    for (int idx = tid; idx < NPB * G; idx += 256) {
        int nl = idx / G, g = idx % G;
        int nn = node0 + nl;
        xsh[nl][g] = (nn < BB * NN) ? xT[(size_t)nn * G + g] : 0.f;
    }
    __syncthreads();

    // 256 threads = 16 nodes x 16 outputs (o = set*8 + which*4 + p)
    {
        int nl = tid / 16, o = tid % 16;
        int set = o / 8, which = (o / 4) % 2, p = o % 4;
        float acc = 0.f;
        if (set == 0 || aB) {
#pragma unroll
            for (int g = 0; g < G; ++g) acc += ash[set][which][p][g] * xsh[nl][g];
        }
        ysh[nl][o] = acc;
    }
    __syncthreads();

    if (tid < NPB * 4) {
        int nl = tid / 4, q = tid % 4;
        int node = node0 + nl;
        if (node < BB * NN) {
            int base = (q / 2) * 8 + (q % 2) * 4;   // q: 0=s1A,1=s2A,2=s1B,3=s2B
            float4 v = make_float4(ysh[nl][base + 0], ysh[nl][base + 1],
                                   ysh[nl][base + 2], ysh[nl][base + 3]);
            if (q == 0) s1A[node] = v;
            else if (q == 1) s2A[node] = v;
            else if (q == 2) { if (aB) s1B[node] = v; }
            else             { if (aB) s2B[node] = v; }
        }
    }
}

// ---------- att = max over spatial ----------
__global__ void k_attmax(const float* __restrict__ d, float* __restrict__ att) {
    int wid = blockIdx.x;
    int lane = threadIdx.x;
    const float4* row = (const float4*)(d + (size_t)wid * NN);
    float m = -1e30f;
    for (int q = lane; q < 625; q += 64) {
        float4 f = row[q];
        m = fmaxf(m, fmaxf(fmaxf(f.x, f.y), fmaxf(f.z, f.w)));
    }
    for (int s = 32; s >= 1; s >>= 1) m = fmaxf(m, __shfl_xor(m, s));
    if (lane == 0) att[wid] = m;
}

// ---------- channel-attention MLP ----------
__launch_bounds__(128)
__global__ void k_camlp(const float* __restrict__ att,
                        const float* __restrict__ w1, const float* __restrict__ b1,
                        const float* __restrict__ w2, const float* __restrict__ b2,
                        float* __restrict__ attf) {
    __shared__ float a[128];
    __shared__ float h[128];
    int b = blockIdx.x, t = threadIdx.x;
    a[t] = att[b * 128 + t];
    __syncthreads();
    float acc = b1[t];
    const float* wr = w1 + (size_t)t * 128;
    for (int k = 0; k < 128; ++k) acc += a[k] * wr[k];
    h[t] = fmaxf(acc, 0.f);
    __syncthreads();
    float acc2 = b2[t];
    const float* wr2 = w2 + (size_t)t * 128;
    for (int k = 0; k < 128; ++k) acc2 += h[k] * wr2[k];
    attf[b * 128 + t] = sigmoidf_(acc2);
}

// ---------- MLP ----------
__global__ void k_mlp1(const float* __restrict__ flat, const float* __restrict__ w,
                       const float* __restrict__ bias, float* __restrict__ out) {
    int wid = blockIdx.x;
    int lane = threadIdx.x;
    int o = wid % 512;
    int b = wid / 512;
    const float* fr = flat + b * NN;
    const float* wr = w + (size_t)o * NN;
    float acc = 0.f;
    for (int n = lane; n < NN; n += 64) acc += fr[n] * wr[n];
    for (int s = 32; s >= 1; s >>= 1) acc += __shfl_xor(acc, s);
    if (lane == 0) out[wid] = fmaxf(acc + bias[o], 0.0f);
}

__global__ void k_mlp2(const float* __restrict__ m, const float* __restrict__ w,
                       const float* __restrict__ bias, float* __restrict__ out) {
    int wid = blockIdx.x;
    int lane = threadIdx.x;
    int o = wid % 5;
    int b = wid / 5;
    const float* mr = m + b * 512;
    const float* wr = w + o * 512;
    float acc = 0.f;
    for (int k = lane; k < 512; k += 64) acc += mr[k] * wr[k];
    for (int s = 32; s >= 1; s >>= 1) acc += __shfl_xor(acc, s);
    if (lane == 0) out[wid] = 1.0f / (1.0f + expf(-(acc + bias[o])));
}

extern "C" void kernel_launch(void* const* d_in, const int* in_sizes, int n_in,
                              void* d_out, int out_size, void* d_ws, size_t ws_size,
                              hipStream_t stream) {
    const float* x       = (const float*)d_in[0];
    const float* Slist   = (const float*)d_in[1];
    const float* enc_w1  = (const float*)d_in[2];
    const float* enc_b1  = (const float*)d_in[3];
    const float* enc_w2  = (const float*)d_in[4];
    const float* enc_b2  = (const float*)d_in[5];
    const float* d0_a = (const float*)d_in[6];  const float* d0_W = (const float*)d_in[7];  const float* d0_b = (const float*)d_in[8];
    const float* d1_a = (const float*)d_in[9];  const float* d1_W = (const float*)d_in[10]; const float* d1_b = (const float*)d_in[11];
    const float* u0_a = (const float*)d_in[12]; const float* u0_W = (const float*)d_in[13]; const float* u0_b = (const float*)d_in[14];
    const float* u1_a = (const float*)d_in[15]; const float* u1_W = (const float*)d_in[16]; const float* u1_b = (const float*)d_in[17];
    const float* s0_a = (const float*)d_in[18]; const float* s0_W = (const float*)d_in[19]; const float* s0_b = (const float*)d_in[20];
    const float* s1_a = (const float*)d_in[21]; const float* s1_W = (const float*)d_in[22]; const float* s1_b = (const float*)d_in[23];
    const float* ca_w1 = (const float*)d_in[24]; const float* ca_b1 = (const float*)d_in[25];
    const float* ca_w2 = (const float*)d_in[26]; const float* ca_b2 = (const float*)d_in[27];
    const float* dec_w1 = (const float*)d_in[28]; const float* dec_b1 = (const float*)d_in[29];
    const float* dec_w2 = (const float*)d_in[30]; const float* dec_b2 = (const float*)d_in[31];
    const float* mlp_w1 = (const float*)d_in[32]; const float* mlp_b1 = (const float*)d_in[33];
    const float* mlp_w2 = (const float*)d_in[34]; const float* mlp_b2 = (const float*)d_in[35];
    float* out = (float*)d_out;

    // ---- workspace layout (f32 elements) ----
    float* ws = (float*)d_ws;
    size_t off = 0;
    auto alloc = [&](size_t n) { float* p = ws + off; off += n; return p; };
    float* h1    = alloc((size_t)BB * 32 * NN);
    float* xT_f0 = alloc((size_t)BB * NN * 32);
    float* xT_f1 = alloc((size_t)BB * NN * 64);
    float* xT_f2 = alloc((size_t)BB * NN * 32);
    float* xT_g1 = alloc((size_t)BB * NN * 64);
    float* g2    = alloc((size_t)BB * 128 * NN);
    unsigned long long* segb = (unsigned long long*)alloc((size_t)2 * BB * NN * 2);
    int*   cols = (int*)alloc((size_t)2 * BB * NN * SEGSTRIDE);
    float* valsb = alloc((size_t)2 * BB * NN * SEGSTRIDE);
    float4* s1_d0 = (float4*)alloc(4 * BB * NN); float4* s2_d0 = (float4*)alloc(4 * BB * NN);
    float4* s1_s0 = (float4*)alloc(4 * BB * NN); float4* s2_s0 = (float4*)alloc(4 * BB * NN);
    float4* s1_d1 = (float4*)alloc(4 * BB * NN); float4* s2_d1 = (float4*)alloc(4 * BB * NN);
    float4* s1_sc1= (float4*)alloc(4 * BB * NN); float4* s2_sc1= (float4*)alloc(4 * BB * NN);
    float4* s1_u0 = (float4*)alloc(4 * BB * NN); float4* s2_u0 = (float4*)alloc(4 * BB * NN);
    float4* s1_u1 = (float4*)alloc(4 * BB * NN); float4* s2_u1 = (float4*)alloc(4 * BB * NN);
    float* z1_d0  = alloc((size_t)BB * NN * PP * 32);
    float* z1_s0  = alloc((size_t)BB * NN * PP * 32);
    float* z1_d1  = alloc((size_t)BB * NN * PP * 64);
    float* z1_sc1 = alloc((size_t)BB * NN * PP * 64);
    float* z1_u0  = alloc((size_t)BB * NN * PP * 32);
    float* z1_u1  = alloc((size_t)BB * NN * PP * 64);
    float* att   = alloc(BB * 128);
    float* attf  = alloc(BB * 128);
    float* dec1o = alloc((size_t)BB * 32 * NN);
    float* dec2o = alloc((size_t)BB * NN);
    float* mbuf  = alloc((size_t)BB * 512);
    float* wre1  = alloc(32 * 3 * 9);
    float* wre2  = alloc(32 * 32 * 9);
    float* wre3  = alloc(32 * 128 * 9);
    float* wre4  = alloc(1 * 32 * 9);
    float* partial = alloc((size_t)8 * BB * 32 * NN);
    (void)ws_size;

    const int T = 256;
    const int NNODE = BB * NN;          // 5000
    const unsigned long long* segb0 = segb;
    const unsigned long long* segb1 = segb + (size_t)NNODE;
    const int* col0 = cols;
    const int* col1 = cols + (size_t)NNODE * SEGSTRIDE;
    const float* val0 = valsb;
    const float* val1 = valsb + (size_t)NNODE * SEGSTRIDE;

    // 0. weight repack + encoder
    k_repack<<<cdiv(32 * 128 * 9, T), T, 0, stream>>>(enc_w1, enc_w2, dec_w1, dec_w2,
                                                      wre1, wre2, wre3, wre4);
    k_conv_enc1<<<BB * 4 * PXB2, 256, 0, stream>>>(x, wre1, enc_b1, h1);
    k_conv_part<8><<<BB * 4 * 4 * PXB2, 256, 0, stream>>>(h1, wre2, nullptr, partial,
                                                          32, 32, 4, 4, 8, 0.0f);
    k_conv_reduce<<<cdiv(BB * 32 * NN, T), T, 0, stream>>>(partial, enc_b2, nullptr, xT_f0, 32, 4);
    // 1. adjacency
    k_build_adj<<<cdiv(2 * NNODE * SEGS, 4), 256, 0, stream>>>(Slist, segb, cols, valsb);
    // 2. s1/s2 on f0 for d0 + s0 (coalesced block kernel)
    k_s1s2T<32><<<cdiv(NNODE, 16), 256, 0, stream>>>(xT_f0, d0_a, s1_d0, s2_d0,
                                                     s0_a, s1_s0, s2_s0);
    // 3. sparse {d0,s0} on (f0,S0)
    k_zgather<32,1><<<NNODE / 4, 256, 0, stream>>>(xT_f0, segb0, col0, val0,
                                                   s1_d0, s2_d0, z1_d0,
                                                   s1_s0, s2_s0, z1_s0);
    // 4. dense f1; emit s1s2 for d1, sc1
    k_dense<32,32,16,0,0,2><<<cdiv(NNODE, 16), 256, 0, stream>>>(
        xT_f0, z1_d0, d0_W, d0_b, nullptr, nullptr, nullptr, nullptr,
        d1_a, s1_d1, s2_d1, s1_a, s1_sc1, s2_sc1, xT_f1);
    // 5. sparse {d1,sc1} on (f1,S1)
    k_zgather<64,1><<<NNODE / 4, 256, 0, stream>>>(xT_f1, segb1, col1, val1,
                                                   s1_d1, s2_d1, z1_d1,
                                                   s1_sc1, s2_sc1, z1_sc1);
    // 6. dense f2; emit s1s2 for u0
    k_dense<64,32,8,0,0,1><<<cdiv(NNODE, 32), 256, 0, stream>>>(
        xT_f1, z1_d1, d1_W, d1_b, nullptr, nullptr, nullptr, nullptr,
        u0_a, s1_u0, s2_u0, nullptr, nullptr, nullptr, xT_f2);
    // 7. sparse {u0} on (f2,S1)
    k_zgather<32,0><<<NNODE / 4, 256, 0, stream>>>(xT_f2, segb1, col1, val1,
                                                   s1_u0, s2_u0, z1_u0,
                                                   nullptr, nullptr, nullptr);
    // 8. dense g1 = proj(f2)+proj(f1); emit s1s2 for u1
    k_dense<32,64,16,1,0,1><<<cdiv(NNODE, 16), 256, 0, stream>>>(
        xT_f2, z1_u0, u0_W, u0_b, xT_f1, z1_sc1, s1_W, s1_b,
        u1_a, s1_u1, s2_u1, nullptr, nullptr, nullptr, xT_g1);
    // 9. sparse {u1} on (g1,S0)
    k_zgather<64,0><<<NNODE / 4, 256, 0, stream>>>(xT_g1, segb0, col0, val0,
                                                   s1_u1, s2_u1, z1_u1,
                                                   nullptr, nullptr, nullptr);
    // 10. dense g2 = proj(g1)+proj(f0), head-split grid (channel-major)
    k_dense_psplit<64,32,32,1,1><<<cdiv(NNODE, 8) * PP, 256, 0, stream>>>(
        xT_g1, z1_u1, u1_W, u1_b, xT_f0, z1_s0, s0_W, s0_b, g2);
    // 11. channel attention (scale fused into dec conv1)
    k_attmax<<<BB * 128, 64, 0, stream>>>(g2, att);
    k_camlp<<<BB, 128, 0, stream>>>(att, ca_w1, ca_b1, ca_w2, ca_b2, attf);
    // 12. decoder convs (pad -999)
    k_conv_part<8><<<BB * 8 * 4 * PXB2, 256, 0, stream>>>(g2, wre3, attf, partial,
                                                          128, 32, 4, 8, 16, -999.0f);
    k_conv_reduce<<<cdiv(BB * 32 * NN, T), T, 0, stream>>>(partial, dec_b1, dec1o, nullptr, 32, 8);
    k_conv_dec2<<<BB * PXB2, 256, 0, stream>>>(dec1o, wre4, dec_b2, dec2o);
    // 13. MLP head
    k_mlp1<<<BB * 512, 64, 0, stream>>>(dec2o, mlp_w1, mlp_b1, mbuf);
    k_mlp2<<<BB * 5, 64, 0, stream>>>(mbuf, mlp_w2, mlp_b2, out);
}

// Round 10
// 274.270 us; speedup vs baseline: 1.3058x; 1.1161x over previous
//
#include <hip/hip_runtime.h>
#include <hip/hip_bf16.h>
#include <math.h>

// ---- problem constants ----
#define BB 2
#define HH 50
#define WW 50
#define NN 2500            // H*W
#define PP 4
#define LRELU_SLOPE 0.2f
#define ZTOL 1e-9f
#define PXB2 10            // ceil(2500/256)
#define SEGS 5             // adjacency segments per row
#define SEGCAP 32          // slots per segment
#define SEGSTRIDE (SEGS * SEGCAP)   // 160

static inline int cdiv(int a, int b) { return (a + b - 1) / b; }

__device__ __forceinline__ float sigmoidf_(float v) { return 1.0f / (1.0f + expf(-v)); }

// ---------- weight repack: w[oc][ic][tap] -> wre[(ic*9+tap)*OC + oc] ----------
__global__ void k_repack(const float* __restrict__ e1, const float* __restrict__ e2,
                         const float* __restrict__ dd1, const float* __restrict__ dd2,
                         float* __restrict__ r1, float* __restrict__ r2,
                         float* __restrict__ r3, float* __restrict__ r4) {
    int i = blockIdx.x * blockDim.x + threadIdx.x;
    if (i < 32 * 3 * 9)  { int oc = i / 27;  int rem = i % 27;  int ic = rem / 9; int tp = rem % 9; r1[(ic * 9 + tp) * 32 + oc] = e1[i]; }
    if (i < 32 * 32 * 9) { int oc = i / 288; int rem = i % 288; int ic = rem / 9; int tp = rem % 9; r2[(ic * 9 + tp) * 32 + oc] = e2[i]; }
    if (i < 32 * 128 * 9){ int oc = i / 1152;int rem = i % 1152;int ic = rem / 9; int tp = rem % 9; r3[(ic * 9 + tp) * 32 + oc] = dd1[i]; }
    if (i < 1 * 32 * 9)  { int oc = 0;       int rem = i;       int ic = rem / 9; int tp = rem % 9; r4[(ic * 9 + tp) * 1  + oc] = dd2[i]; }
}

// ---------- enc conv1 (3->32) with fused sigmoid ----------
__launch_bounds__(256)
__global__ void k_conv_enc1(const float* __restrict__ x, const float* __restrict__ wre,
                            const float* __restrict__ bias, float* __restrict__ out) {
    int bx = blockIdx.x;
    int pxb = bx % PXB2;
    int ocg = (bx / PXB2) % 4;
    int b = bx / (PXB2 * 4);
    int px = pxb * 256 + threadIdx.x;
    bool valid = px < NN;
    int xx0 = px % WW, yy0 = px / WW;
    float acc[8];
#pragma unroll
    for (int o = 0; o < 8; ++o) acc[o] = 0.f;
    for (int ic = 0; ic < 3; ++ic) {
        const float* ip = x + ((size_t)(b * 3 + ic)) * NN;
        float v[9];
#pragma unroll
        for (int ky = 0; ky < 3; ++ky) {
            int yy = yy0 + ky - 1;
#pragma unroll
            for (int kx = 0; kx < 3; ++kx) {
                int xx = xx0 + kx - 1;
                bool ok = valid && yy >= 0 && yy < HH && xx >= 0 && xx < WW;
                v[ky * 3 + kx] = ok ? sigmoidf_(ip[yy * WW + xx]) : 0.f;
            }
        }
        const float* wp = wre + (size_t)ic * 9 * 32 + ocg * 8;
#pragma unroll
        for (int tp = 0; tp < 9; ++tp) {
            float vv = v[tp];
#pragma unroll
            for (int o = 0; o < 8; ++o) acc[o] += wp[tp * 32 + o] * vv;
        }
    }
    if (valid) {
#pragma unroll
        for (int o = 0; o < 8; ++o) {
            int oc = ocg * 8 + o;
            out[((size_t)(b * 32 + oc)) * NN + px] = fmaxf(acc[o] + bias[oc], 0.f);
        }
    }
}

// ---------- generic chunked conv3x3 partials ----------
template<int OCT>
__launch_bounds__(256)
__global__ void k_conv_part(const float* __restrict__ in, const float* __restrict__ wre,
                            const float* __restrict__ attscale,
                            float* __restrict__ part, int Cin, int OC, int nocg,
                            int nchunks, int icchunk, float padval) {
    int bx = blockIdx.x;
    int pxb = bx % PXB2; bx /= PXB2;
    int ocg = bx % nocg; bx /= nocg;
    int chunk = bx % nchunks;
    int b = bx / nchunks;
    int px = pxb * 256 + threadIdx.x;
    bool valid = px < NN;
    int xx0 = px % WW, yy0 = px / WW;

    float acc[OCT];
#pragma unroll
    for (int o = 0; o < OCT; ++o) acc[o] = 0.f;

    int ic0 = chunk * icchunk;
    int ic1 = ic0 + icchunk; if (ic1 > Cin) ic1 = Cin;

    for (int ic = ic0; ic < ic1; ++ic) {
        const float* ip = in + ((size_t)(b * Cin + ic)) * NN;
        float attv = attscale ? attscale[b * Cin + ic] : 1.f;
        float v[9];
#pragma unroll
        for (int ky = 0; ky < 3; ++ky) {
            int yy = yy0 + ky - 1;
#pragma unroll
            for (int kx = 0; kx < 3; ++kx) {
                int xx = xx0 + kx - 1;
                bool ok = valid && yy >= 0 && yy < HH && xx >= 0 && xx < WW;
                v[ky * 3 + kx] = ok ? ip[yy * WW + xx] * attv : padval;
            }
        }
        const float* wp = wre + (size_t)ic * 9 * OC + ocg * OCT;
#pragma unroll
        for (int tp = 0; tp < 9; ++tp) {
            float vv = v[tp];
#pragma unroll
            for (int o = 0; o < OCT; ++o) acc[o] += wp[tp * OC + o] * vv;
        }
    }
    if (valid) {
#pragma unroll
        for (int o = 0; o < OCT; ++o)
            part[(((size_t)chunk * BB + b) * OC + ocg * OCT + o) * NN + px] = acc[o];
    }
}

// ---------- reduce chunks + bias + relu; dual-layout write ----------
__global__ void k_conv_reduce(const float* __restrict__ part, const float* __restrict__ bias,
                              float* __restrict__ out, float* __restrict__ xTout,
                              int OCr, int nchunks) {
    int idx = blockIdx.x * blockDim.x + threadIdx.x;
    int total = BB * OCr * NN;
    if (idx >= total) return;
    int px = idx % NN;
    int oc = (idx / NN) % OCr;
    int b = idx / (NN * OCr);
    float s = bias[oc];
    for (int c = 0; c < nchunks; ++c)
        s += part[(((size_t)c * BB + b) * OCr + oc) * NN + px];
    s = fmaxf(s, 0.f);
    if (out)   out[((size_t)(b * OCr + oc)) * NN + px] = s;
    if (xTout) xTout[((size_t)b * NN + px) * OCr + oc] = s;
}

// ---------- dec conv2 (32->1) single pass ----------
__launch_bounds__(256)
__global__ void k_conv_dec2(const float* __restrict__ in, const float* __restrict__ wre,
                            const float* __restrict__ bias, float* __restrict__ out) {
    int pxb = blockIdx.x % PXB2;
    int b = blockIdx.x / PXB2;
    int px = pxb * 256 + threadIdx.x;
    bool valid = px < NN;
    int xx0 = px % WW, yy0 = px / WW;
    float acc = 0.f;
    for (int ic = 0; ic < 32; ++ic) {
        const float* ip = in + ((size_t)(b * 32 + ic)) * NN;
#pragma unroll
        for (int ky = 0; ky < 3; ++ky) {
            int yy = yy0 + ky - 1;
#pragma unroll
            for (int kx = 0; kx < 3; ++kx) {
                int xx = xx0 + kx - 1;
                bool ok = valid && yy >= 0 && yy < HH && xx >= 0 && xx < WW;
                float v = ok ? ip[yy * WW + xx] : -999.0f;
                acc += v * wre[ic * 9 + ky * 3 + kx];
            }
        }
    }
    if (valid) out[(size_t)b * NN + px] = fmaxf(acc + bias[0], 0.f);
}

// ---------- segmented adjacency build ----------
__launch_bounds__(256)
__global__ void k_build_adj(const float* __restrict__ S,
                            unsigned long long* __restrict__ segb,
                            int* __restrict__ cols, float* __restrict__ vals) {
    int wg = blockIdx.x * 4 + (threadIdx.x >> 6);
    int lane = threadIdx.x & 63;
    int row = wg / SEGS;
    int seg = wg % SEGS;
    if (row >= 2 * BB * NN) return;
    int i = row % NN;
    int b = (row / NN) % BB;
    int s = row / (NN * BB);
    const float4* Srow = (const float4*)(S + (((size_t)(b * 2 + s)) * NN + i) * NN);
    int qb = seg * 125;

    float4 f1 = Srow[qb + lane];
    bool l2ok = lane < 61;
    float4 f2 = make_float4(0.f, 0.f, 0.f, 0.f);
    if (l2ok) f2 = Srow[qb + 64 + lane];

    unsigned long long below = (lane == 63) ? 0x7fffffffffffffffull
                                            : ((1ull << lane) - 1ull);
    unsigned long long a0 = __ballot(fabsf(f1.x) > ZTOL);
    unsigned long long a1 = __ballot(fabsf(f1.y) > ZTOL);
    unsigned long long a2 = __ballot(fabsf(f1.z) > ZTOL);
    unsigned long long a3 = __ballot(fabsf(f1.w) > ZTOL);
    unsigned long long c0 = __ballot(l2ok && fabsf(f2.x) > ZTOL);
    unsigned long long c1 = __ballot(l2ok && fabsf(f2.y) > ZTOL);
    unsigned long long c2 = __ballot(l2ok && fabsf(f2.z) > ZTOL);
    unsigned long long c3 = __ballot(l2ok && fabsf(f2.w) > ZTOL);

    int n1 = __popcll(a0) + __popcll(a1) + __popcll(a2) + __popcll(a3);
    int total = n1 + __popcll(c0) + __popcll(c1) + __popcll(c2) + __popcll(c3);

    size_t base = (size_t)row * SEGSTRIDE + seg * SEGCAP;
    {
        int idx = __popcll(a0 & below) + __popcll(a1 & below) +
                  __popcll(a2 & below) + __popcll(a3 & below);
        int j0 = (qb + lane) * 4;
        if ((a0 >> lane) & 1) { if (idx < SEGCAP) { cols[base + idx] = j0 + 0; vals[base + idx] = f1.x; } ++idx; }
        if ((a1 >> lane) & 1) { if (idx < SEGCAP) { cols[base + idx] = j0 + 1; vals[base + idx] = f1.y; } ++idx; }
        if ((a2 >> lane) & 1) { if (idx < SEGCAP) { cols[base + idx] = j0 + 2; vals[base + idx] = f1.z; } ++idx; }
        if ((a3 >> lane) & 1) { if (idx < SEGCAP) { cols[base + idx] = j0 + 3; vals[base + idx] = f1.w; } ++idx; }
    }
    {
        int idx = n1 + __popcll(c0 & below) + __popcll(c1 & below) +
                       __popcll(c2 & below) + __popcll(c3 & below);
        int j1 = (qb + 64 + lane) * 4;
        if ((c0 >> lane) & 1) { if (idx < SEGCAP) { cols[base + idx] = j1 + 0; vals[base + idx] = f2.x; } ++idx; }
        if ((c1 >> lane) & 1) { if (idx < SEGCAP) { cols[base + idx] = j1 + 1; vals[base + idx] = f2.y; } ++idx; }
        if ((c2 >> lane) & 1) { if (idx < SEGCAP) { cols[base + idx] = j1 + 2; vals[base + idx] = f2.z; } ++idx; }
        if ((c3 >> lane) & 1) { if (idx < SEGCAP) { cols[base + idx] = j1 + 3; vals[base + idx] = f2.w; } ++idx; }
    }
    if (lane == 0) {
        int t = total > SEGCAP ? SEGCAP : total;
        ((unsigned char*)segb)[(size_t)row * 8 + seg] = (unsigned char)t;
    }
}

// ---------- adjacency reader ----------
__device__ __forceinline__ void adj_load(const unsigned long long* __restrict__ segb,
                                         const int* __restrict__ cols,
                                         const float* __restrict__ vals,
                                         int node, int lane,
                                         int& cnt, int& colr, float& valr) {
    unsigned long long sb = segb[node];
    int c0 = (int)(sb & 0xff), c1 = (int)((sb >> 8) & 0xff), c2 = (int)((sb >> 16) & 0xff),
        c3 = (int)((sb >> 24) & 0xff), c4 = (int)((sb >> 32) & 0xff);
    int cum1 = c0, cum2 = cum1 + c1, cum3 = cum2 + c2, cum4 = cum3 + c3;
    cnt = cum4 + c4; if (cnt > 64) cnt = 64;
    int seg = 0, basec = 0;
    if (lane >= cum1) { seg = 1; basec = cum1; }
    if (lane >= cum2) { seg = 2; basec = cum2; }
    if (lane >= cum3) { seg = 3; basec = cum3; }
    if (lane >= cum4) { seg = 4; basec = cum4; }
    colr = 0; valr = 0.f;
    if (lane < cnt) {
        size_t sl = (size_t)node * SEGSTRIDE + seg * SEGCAP + (lane - basec);
        colr = cols[sl];
        valr = vals[sl];
    }
}

// ---------- per-head masked softmax * S ----------
__device__ __forceinline__ float4 softmax4(float4 s1f, float4 s2f, int lane, int cnt, float valr) {
    float e[PP] = { s1f.x + s2f.x, s1f.y + s2f.y, s1f.z + s2f.z, s1f.w + s2f.w };
    float w[PP];
#pragma unroll
    for (int p = 0; p < PP; ++p) {
        float v = e[p];
        v = (v < 0.f) ? LRELU_SLOPE * v : v;
        v = (lane < cnt) ? v : -1e30f;
        float mx = v;
#pragma unroll
        for (int m = 32; m >= 1; m >>= 1) mx = fmaxf(mx, __shfl_xor(mx, m));
        float ex = (lane < cnt) ? expf(v - mx) : 0.f;
        float sm = ex;
#pragma unroll
        for (int m = 32; m >= 1; m >>= 1) sm += __shfl_xor(sm, m);
        w[p] = (cnt > 0) ? ex / sm * valr : 0.f;
    }
    return make_float4(w[0], w[1], w[2], w[3]);
}

// ---------- emit s1/s2 (lane holds y element `lane`, PF<=64) ----------
template<int PF>
__device__ __forceinline__ void emit_one(const float* __restrict__ a,
                                         float4* __restrict__ s1E, float4* __restrict__ s2E,
                                         float yl, int lane, int node) {
    float r1[PP], r2[PP];
#pragma unroll
    for (int p = 0; p < PP; ++p) {
        float v1 = (lane < PF) ? a[p * 2 * PF + lane] * yl : 0.f;
        float v2 = (lane < PF) ? a[p * 2 * PF + PF + lane] * yl : 0.f;
#pragma unroll
        for (int m = 32; m >= 1; m >>= 1) { v1 += __shfl_xor(v1, m); v2 += __shfl_xor(v2, m); }
        r1[p] = v1; r2[p] = v2;
    }
    if (lane == 0) {
        s1E[node] = make_float4(r1[0], r1[1], r1[2], r1[3]);
        s2E[node] = make_float4(r2[0], r2[1], r2[2], r2[3]);
    }
}

// ---------- merged GAT layer: sparse (1 node/wave, barrier-free) + dense (LDS-tiled) ----------
// y = bias + x*W0 + z1*W1 [+ xB*V0 + z1B*V1]; emits next-layer s1/s2; optionally stores
// a second z-set (z1Zout) for use as a later layer's B operand.
template<int G, int F, int DUALZ, int GB, int DUALD, int ES, int R>
__launch_bounds__(256)
__global__ void k_gat_layer(const float* __restrict__ xT,
                            const unsigned long long* __restrict__ segb,
                            const int* __restrict__ cols, const float* __restrict__ vals,
                            const float4* __restrict__ s1A, const float4* __restrict__ s2A,
                            const float4* __restrict__ s1Z, const float4* __restrict__ s2Z,
                            float* __restrict__ z1Zout,
                            const float* __restrict__ Wf, const float* __restrict__ bias,
                            const float* __restrict__ xB, const float* __restrict__ z1B,
                            const float* __restrict__ WfB, const float* __restrict__ biasB,
                            const float* __restrict__ aE0, float4* __restrict__ s1E0, float4* __restrict__ s2E0,
                            const float* __restrict__ aE1, float4* __restrict__ s1E1, float4* __restrict__ s2E1,
                            float* __restrict__ dst) {
    constexpr int PF = PP * F;
    constexpr int HP = PP / R;                  // heads per dense round
    constexpr int WA = HP * 2 * G * F;
    constexpr int WB = DUALD ? HP * 2 * GB * F : 0;
    __shared__ int    csh[4][64];
    __shared__ float4 wAsh[4][64];
    __shared__ float4 wZsh[DUALZ ? 4 : 1][DUALZ ? 64 : 1];
    __shared__ float  xAsh[4][G + 1];
    __shared__ float  z1Ash[4][PP * G + 1];
    __shared__ float  xBsh[DUALD ? 4 : 1][DUALD ? (GB + 1) : 1];
    __shared__ float  z1Bsh[DUALD ? 4 : 1][DUALD ? (PP * GB + 1) : 1];
    __shared__ float  Wsh[WA + WB];
    __shared__ float  ysh[ES ? 4 : 1][ES ? (PF + 1) : 1];

    int tid = threadIdx.x;
    int w = tid >> 6, lane = tid & 63;
    int node0 = blockIdx.x * 4;                 // NNODE=5000 divisible by 4

    // ---- sparse phase: wave w owns node node0+w (no cross-wave deps) ----
    {
        int node = node0 + w;
        int b = node / NN;
        if (lane < G) xAsh[w][lane] = xT[(size_t)node * G + lane];
        int cnt, colr; float valr;
        adj_load(segb, cols, vals, node, lane, cnt, colr, valr);
        float4 s2fA = make_float4(0.f, 0.f, 0.f, 0.f);
        float4 s2fZ = make_float4(0.f, 0.f, 0.f, 0.f);
        if (lane < cnt) {
            s2fA = s2A[(size_t)b * NN + colr];
            if (DUALZ) s2fZ = s2Z[(size_t)b * NN + colr];
        }
        csh[w][lane] = colr;
        wAsh[w][lane] = softmax4(s1A[node], s2fA, lane, cnt, valr);
        if (DUALZ) wZsh[w][lane] = softmax4(s1Z[node], s2fZ, lane, cnt, valr);

        constexpr int STEP = (G == 32) ? 2 : 1;
        int sl = (G == 32) ? (lane >> 5) : 0;
        int g  = (G == 32) ? (lane & 31) : lane;
        float zA[PP] = {0.f, 0.f, 0.f, 0.f};
        float zZ[PP] = {0.f, 0.f, 0.f, 0.f};
        for (int jj = sl; jj < cnt; jj += STEP) {
            float xv = xT[((size_t)b * NN + csh[w][jj]) * G + g];
            float4 wa = wAsh[w][jj];
            zA[0] += wa.x * xv; zA[1] += wa.y * xv; zA[2] += wa.z * xv; zA[3] += wa.w * xv;
            if (DUALZ) {
                float4 wz = wZsh[w][jj];
                zZ[0] += wz.x * xv; zZ[1] += wz.y * xv; zZ[2] += wz.z * xv; zZ[3] += wz.w * xv;
            }
        }
        if (G == 32) {
#pragma unroll
            for (int p = 0; p < PP; ++p) {
                zA[p] += __shfl_xor(zA[p], 32);
                if (DUALZ) zZ[p] += __shfl_xor(zZ[p], 32);
            }
        }
        if (sl == 0) {
#pragma unroll
            for (int p = 0; p < PP; ++p) {
                z1Ash[w][p * G + g] = zA[p];
                if (DUALZ) z1Zout[((size_t)node * PP + p) * G + g] = zZ[p];
            }
        }
    }
    // stage dense B operands (independent of sparse results)
    if (DUALD) {
        for (int idx = tid; idx < 4 * GB; idx += 256) {
            int nl = idx / GB, g = idx % GB;
            xBsh[nl][g] = xB[(size_t)(node0 + nl) * GB + g];
        }
        for (int idx = tid; idx < 4 * PP * GB; idx += 256) {
            int nl = idx / (PP * GB), r2 = idx % (PP * GB);
            z1Bsh[nl][r2] = z1B[(size_t)(node0 + nl) * PP * GB + r2];
        }
    }

    // ---- dense phase: R rounds over head groups ----
    for (int r = 0; r < R; ++r) {
        __syncthreads();
        for (int idx = tid; idx < WA; idx += 256)
            Wsh[idx] = Wf[(size_t)(r * HP) * 2 * G * F + idx];
        if (DUALD)
            for (int idx = tid; idx < WB; idx += 256)
                Wsh[WA + idx] = WfB[(size_t)(r * HP) * 2 * GB * F + idx];
        __syncthreads();

        constexpr int ITEMS = 4 * HP * F;
        if (tid < ITEMS) {
            int nl = tid / (HP * F);
            int rem = tid % (HP * F);
            int ph = rem / F, fi = rem % F;
            int p = r * HP + ph;
            const float* W0 = Wsh + ph * 2 * G * F;
            const float* W1 = W0 + G * F;
            float y = bias[fi] + (DUALD ? biasB[fi] : 0.f);
#pragma unroll
            for (int g = 0; g < G; ++g)
                y += xAsh[nl][g] * W0[g * F + fi] + z1Ash[nl][p * G + g] * W1[g * F + fi];
            if (DUALD) {
                const float* V0 = Wsh + WA + ph * 2 * GB * F;
                const float* V1 = V0 + GB * F;
#pragma unroll
                for (int g = 0; g < GB; ++g)
                    y += xBsh[nl][g] * V0[g * F + fi] + z1Bsh[nl][p * GB + g] * V1[g * F + fi];
            }
            int oc = p * F + fi;
            dst[(size_t)(node0 + nl) * PF + oc] = y;
            if (ES) ysh[nl][oc] = y;
        }
    }

    if (ES) {
        __syncthreads();
        float yl = (lane < PF) ? ysh[w][lane] : 0.f;
        emit_one<PF>(aE0, s1E0, s2E0, yl, lane, node0 + w);
        if (ES >= 2) emit_one<PF>(aE1, s1E1, s2E1, yl, lane, node0 + w);
    }
}

// ---------- sparse-only gather (L4): softmax + neighbor gather -> z1 ----------
template<int G, int DUAL>
__launch_bounds__(256)
__global__ void k_zgather(const float* __restrict__ xT,
                          const unsigned long long* __restrict__ segb,
                          const int* __restrict__ cols, const float* __restrict__ vals,
                          const float4* __restrict__ s1A, const float4* __restrict__ s2A,
                          float* __restrict__ z1A,
                          const float4* __restrict__ s1B, const float4* __restrict__ s2B,
                          float* __restrict__ z1B) {
    __shared__ int    csh[4][64];
    __shared__ float4 wAsh[4][64];
    __shared__ float4 wBsh[DUAL ? 4 : 1][DUAL ? 64 : 1];

    int w = threadIdx.x >> 6;
    int lane = threadIdx.x & 63;
    int node = blockIdx.x * 4 + w;
    int b = node / NN;

    int cnt, colr; float valr;
    adj_load(segb, cols, vals, node, lane, cnt, colr, valr);
    float4 s2fA = make_float4(0.f, 0.f, 0.f, 0.f);
    float4 s2fB = make_float4(0.f, 0.f, 0.f, 0.f);
    if (lane < cnt) {
        s2fA = s2A[(size_t)b * NN + colr];
        if (DUAL) s2fB = s2B[(size_t)b * NN + colr];
    }
    csh[w][lane] = colr;
    wAsh[w][lane] = softmax4(s1A[node], s2fA, lane, cnt, valr);
    if (DUAL) wBsh[w][lane] = softmax4(s1B[node], s2fB, lane, cnt, valr);

    constexpr int STEP = (G == 32) ? 2 : 1;
    int sl = (G == 32) ? (lane >> 5) : 0;
    int g  = (G == 32) ? (lane & 31) : lane;
    float zA[PP] = {0.f, 0.f, 0.f, 0.f};
    float zB[PP] = {0.f, 0.f, 0.f, 0.f};
    for (int jj = sl; jj < cnt; jj += STEP) {
        float xv = xT[((size_t)b * NN + csh[w][jj]) * G + g];
        float4 wa = wAsh[w][jj];
        zA[0] += wa.x * xv; zA[1] += wa.y * xv; zA[2] += wa.z * xv; zA[3] += wa.w * xv;
        if (DUAL) {
            float4 wb = wBsh[w][jj];
            zB[0] += wb.x * xv; zB[1] += wb.y * xv; zB[2] += wb.z * xv; zB[3] += wb.w * xv;
        }
    }
    if (G == 32) {
#pragma unroll
        for (int p = 0; p < PP; ++p) {
            zA[p] += __shfl_xor(zA[p], 32);
            if (DUAL) zB[p] += __shfl_xor(zB[p], 32);
        }
    }
    if (sl == 0) {
#pragma unroll
        for (int p = 0; p < PP; ++p) {
            z1A[((size_t)node * PP + p) * G + g] = zA[p];
            if (DUAL) z1B[((size_t)node * PP + p) * G + g] = zB[p];
        }
    }
}

// ---------- dense with head-split across blocks (L4, channel-major out) ----------
template<int GA, int GB, int F, int DUAL, int LAY>
__launch_bounds__(256)
__global__ void k_dense_psplit(const float* __restrict__ xA, const float* __restrict__ z1A,
                               const float* __restrict__ WfA, const float* __restrict__ biasA,
                               const float* __restrict__ xB, const float* __restrict__ z1B,
                               const float* __restrict__ WfB, const float* __restrict__ biasB,
                               float* __restrict__ dst) {
    constexpr int PF = PP * F;
    constexpr int NPB = 256 / F;
    constexpr int XA = GA + 1, ZA = GA + 1;
    constexpr int XB = GB + 1, ZB = GB + 1;
    __shared__ float xAsh[NPB * XA];
    __shared__ float z1Ash[NPB * ZA];
    __shared__ float xBsh[DUAL ? NPB * XB : 1];
    __shared__ float z1Bsh[DUAL ? NPB * ZB : 1];
    __shared__ float Wsh[2 * GA * F + (DUAL ? 2 * GB * F : 0)];

    int tid = threadIdx.x;
    int p = blockIdx.x % PP;
    int node0 = (blockIdx.x / PP) * NPB;

    for (int idx = tid; idx < NPB * GA; idx += 256) {
        int nl2 = idx / GA, g = idx % GA;
        int nn = node0 + nl2;
        xAsh[nl2 * XA + g] = (nn < BB * NN) ? xA[(size_t)nn * GA + g] : 0.f;
        z1Ash[nl2 * ZA + g] = (nn < BB * NN) ? z1A[((size_t)nn * PP + p) * GA + g] : 0.f;
    }
    if (DUAL) {
        for (int idx = tid; idx < NPB * GB; idx += 256) {
            int nl2 = idx / GB, g = idx % GB;
            int nn = node0 + nl2;
            xBsh[nl2 * XB + g] = (nn < BB * NN) ? xB[(size_t)nn * GB + g] : 0.f;
            z1Bsh[nl2 * ZB + g] = (nn < BB * NN) ? z1B[((size_t)nn * PP + p) * GB + g] : 0.f;
        }
    }
    for (int idx = tid; idx < 2 * GA * F; idx += 256)
        Wsh[idx] = WfA[(size_t)p * 2 * GA * F + idx];
    if (DUAL)
        for (int idx = tid; idx < 2 * GB * F; idx += 256)
            Wsh[2 * GA * F + idx] = WfB[(size_t)p * 2 * GB * F + idx];
    __syncthreads();

    int fi, nl;
    if (LAY == 1) { nl = tid % NPB; fi = tid / NPB; }
    else          { fi = tid % F;   nl = tid / F;   }
    int node = node0 + nl;
    int b = node / NN, i = node % NN;
    if (node >= BB * NN) return;

    float y = biasA[fi] + (DUAL ? biasB[fi] : 0.f);
    const float* W0 = Wsh;
    const float* W1 = Wsh + GA * F;
#pragma unroll
    for (int g = 0; g < GA; ++g)
        y += xAsh[nl * XA + g] * W0[g * F + fi] + z1Ash[nl * ZA + g] * W1[g * F + fi];
    if (DUAL) {
        const float* V0 = Wsh + 2 * GA * F;
        const float* V1 = V0 + GB * F;
#pragma unroll
        for (int g = 0; g < GB; ++g)
            y += xBsh[nl * XB + g] * V0[g * F + fi] + z1Bsh[nl * ZB + g] * V1[g * F + fi];
    }
    int oc = p * F + fi;
    if (LAY == 1) dst[((size_t)(b * PF + oc)) * NN + i] = y;
    else          dst[(size_t)node * PF + oc] = y;
}

// ---------- s1/s2 for f0: coalesced LDS-staged block kernel ----------
template<int G>
__launch_bounds__(256)
__global__ void k_s1s2T(const float* __restrict__ xT,
                        const float* __restrict__ aA, float4* __restrict__ s1A, float4* __restrict__ s2A,
                        const float* __restrict__ aB, float4* __restrict__ s1B, float4* __restrict__ s2B) {
    constexpr int NPB = 16;
    __shared__ float xsh[NPB][G + 1];
    __shared__ float ash[2][2][PP][G];
    __shared__ float ysh[NPB][17];

    int tid = threadIdx.x;
    int node0 = blockIdx.x * NPB;

    for (int idx = tid; idx < PP * 2 * G; idx += 256) {
        int p = idx / (2 * G), r = idx % (2 * G);
        int which = r / G, g = r % G;
        ash[0][which][p][g] = aA[idx];
        if (aB) ash[1][which][p][g] = aB[idx];
    }
    for (int idx = tid; idx < NPB * G; idx += 256) {
        int nl = idx / G, g = idx % G;
        int nn = node0 + nl;
        xsh[nl][g] = (nn < BB * NN) ? xT[(size_t)nn * G + g] : 0.f;
    }
    __syncthreads();

    {
        int nl = tid / 16, o = tid % 16;
        int set = o / 8, which = (o / 4) % 2, p = o % 4;
        float acc = 0.f;
        if (set == 0 || aB) {
#pragma unroll
            for (int g = 0; g < G; ++g) acc += ash[set][which][p][g] * xsh[nl][g];
        }
        ysh[nl][o] = acc;
    }
    __syncthreads();

    if (tid < NPB * 4) {
        int nl = tid / 4, q = tid % 4;
        int node = node0 + nl;
        if (node < BB * NN) {
            int base = (q / 2) * 8 + (q % 2) * 4;
            float4 v = make_float4(ysh[nl][base + 0], ysh[nl][base + 1],
                                   ysh[nl][base + 2], ysh[nl][base + 3]);
            if (q == 0) s1A[node] = v;
            else if (q == 1) s2A[node] = v;
            else if (q == 2) { if (aB) s1B[node] = v; }
            else             { if (aB) s2B[node] = v; }
        }
    }
}

// ---------- att = max over spatial ----------
__global__ void k_attmax(const float* __restrict__ d, float* __restrict__ att) {
    int wid = blockIdx.x;
    int lane = threadIdx.x;
    const float4* row = (const float4*)(d + (size_t)wid * NN);
    float m = -1e30f;
    for (int q = lane; q < 625; q += 64) {
        float4 f = row[q];
        m = fmaxf(m, fmaxf(fmaxf(f.x, f.y), fmaxf(f.z, f.w)));
    }
    for (int s = 32; s >= 1; s >>= 1) m = fmaxf(m, __shfl_xor(m, s));
    if (lane == 0) att[wid] = m;
}

// ---------- channel-attention MLP ----------
__launch_bounds__(128)
__global__ void k_camlp(const float* __restrict__ att,
                        const float* __restrict__ w1, const float* __restrict__ b1,
                        const float* __restrict__ w2, const float* __restrict__ b2,
                        float* __restrict__ attf) {
    __shared__ float a[128];
    __shared__ float h[128];
    int b = blockIdx.x, t = threadIdx.x;
    a[t] = att[b * 128 + t];
    __syncthreads();
    float acc = b1[t];
    const float* wr = w1 + (size_t)t * 128;
    for (int k = 0; k < 128; ++k) acc += a[k] * wr[k];
    h[t] = fmaxf(acc, 0.f);
    __syncthreads();
    float acc2 = b2[t];
    const float* wr2 = w2 + (size_t)t * 128;
    for (int k = 0; k < 128; ++k) acc2 += h[k] * wr2[k];
    attf[b * 128 + t] = sigmoidf_(acc2);
}

// ---------- MLP ----------
__global__ void k_mlp1(const float* __restrict__ flat, const float* __restrict__ w,
                       const float* __restrict__ bias, float* __restrict__ out) {
    int wid = blockIdx.x;
    int lane = threadIdx.x;
    int o = wid % 512;
    int b = wid / 512;
    const float* fr = flat + b * NN;
    const float* wr = w + (size_t)o * NN;
    float acc = 0.f;
    for (int n = lane; n < NN; n += 64) acc += fr[n] * wr[n];
    for (int s = 32; s >= 1; s >>= 1) acc += __shfl_xor(acc, s);
    if (lane == 0) out[wid] = fmaxf(acc + bias[o], 0.0f);
}

__global__ void k_mlp2(const float* __restrict__ m, const float* __restrict__ w,
                       const float* __restrict__ bias, float* __restrict__ out) {
    int wid = blockIdx.x;
    int lane = threadIdx.x;
    int o = wid % 5;
    int b = wid / 5;
    const float* mr = m + b * 512;
    const float* wr = w + o * 512;
    float acc = 0.f;
    for (int k = lane; k < 512; k += 64) acc += mr[k] * wr[k];
    for (int s = 32; s >= 1; s >>= 1) acc += __shfl_xor(acc, s);
    if (lane == 0) out[wid] = 1.0f / (1.0f + expf(-(acc + bias[o])));
}

extern "C" void kernel_launch(void* const* d_in, const int* in_sizes, int n_in,
                              void* d_out, int out_size, void* d_ws, size_t ws_size,
                              hipStream_t stream) {
    const float* x       = (const float*)d_in[0];
    const float* Slist   = (const float*)d_in[1];
    const float* enc_w1  = (const float*)d_in[2];
    const float* enc_b1  = (const float*)d_in[3];
    const float* enc_w2  = (const float*)d_in[4];
    const float* enc_b2  = (const float*)d_in[5];
    const float* d0_a = (const float*)d_in[6];  const float* d0_W = (const float*)d_in[7];  const float* d0_b = (const float*)d_in[8];
    const float* d1_a = (const float*)d_in[9];  const float* d1_W = (const float*)d_in[10]; const float* d1_b = (const float*)d_in[11];
    const float* u0_a = (const float*)d_in[12]; const float* u0_W = (const float*)d_in[13]; const float* u0_b = (const float*)d_in[14];
    const float* u1_a = (const float*)d_in[15]; const float* u1_W = (const float*)d_in[16]; const float* u1_b = (const float*)d_in[17];
    const float* s0_a = (const float*)d_in[18]; const float* s0_W = (const float*)d_in[19]; const float* s0_b = (const float*)d_in[20];
    const float* s1_a = (const float*)d_in[21]; const float* s1_W = (const float*)d_in[22]; const float* s1_b = (const float*)d_in[23];
    const float* ca_w1 = (const float*)d_in[24]; const float* ca_b1 = (const float*)d_in[25];
    const float* ca_w2 = (const float*)d_in[26]; const float* ca_b2 = (const float*)d_in[27];
    const float* dec_w1 = (const float*)d_in[28]; const float* dec_b1 = (const float*)d_in[29];
    const float* dec_w2 = (const float*)d_in[30]; const float* dec_b2 = (const float*)d_in[31];
    const float* mlp_w1 = (const float*)d_in[32]; const float* mlp_b1 = (const float*)d_in[33];
    const float* mlp_w2 = (const float*)d_in[34]; const float* mlp_b2 = (const float*)d_in[35];
    float* out = (float*)d_out;

    // ---- workspace layout (f32 elements) ----
    float* ws = (float*)d_ws;
    size_t off = 0;
    auto alloc = [&](size_t n) { float* p = ws + off; off += n; return p; };
    float* h1    = alloc((size_t)BB * 32 * NN);
    float* xT_f0 = alloc((size_t)BB * NN * 32);
    float* xT_f1 = alloc((size_t)BB * NN * 64);
    float* xT_f2 = alloc((size_t)BB * NN * 32);
    float* xT_g1 = alloc((size_t)BB * NN * 64);
    float* g2    = alloc((size_t)BB * 128 * NN);
    unsigned long long* segb = (unsigned long long*)alloc((size_t)2 * BB * NN * 2);
    int*   cols = (int*)alloc((size_t)2 * BB * NN * SEGSTRIDE);
    float* valsb = alloc((size_t)2 * BB * NN * SEGSTRIDE);
    float4* s1_d0 = (float4*)alloc(4 * BB * NN); float4* s2_d0 = (float4*)alloc(4 * BB * NN);
    float4* s1_s0 = (float4*)alloc(4 * BB * NN); float4* s2_s0 = (float4*)alloc(4 * BB * NN);
    float4* s1_d1 = (float4*)alloc(4 * BB * NN); float4* s2_d1 = (float4*)alloc(4 * BB * NN);
    float4* s1_sc1= (float4*)alloc(4 * BB * NN); float4* s2_sc1= (float4*)alloc(4 * BB * NN);
    float4* s1_u0 = (float4*)alloc(4 * BB * NN); float4* s2_u0 = (float4*)alloc(4 * BB * NN);
    float4* s1_u1 = (float4*)alloc(4 * BB * NN); float4* s2_u1 = (float4*)alloc(4 * BB * NN);
    float* z1_s0  = alloc((size_t)BB * NN * PP * 32);
    float* z1_sc1 = alloc((size_t)BB * NN * PP * 64);
    float* z1_u1  = alloc((size_t)BB * NN * PP * 64);
    float* att   = alloc(BB * 128);
    float* attf  = alloc(BB * 128);
    float* dec1o = alloc((size_t)BB * 32 * NN);
    float* dec2o = alloc((size_t)BB * NN);
    float* mbuf  = alloc((size_t)BB * 512);
    float* wre1  = alloc(32 * 3 * 9);
    float* wre2  = alloc(32 * 32 * 9);
    float* wre3  = alloc(32 * 128 * 9);
    float* wre4  = alloc(1 * 32 * 9);
    float* partial = alloc((size_t)8 * BB * 32 * NN);
    (void)ws_size;

    const int T = 256;
    const int NNODE = BB * NN;          // 5000
    const unsigned long long* segb0 = segb;
    const unsigned long long* segb1 = segb + (size_t)NNODE;
    const int* col0 = cols;
    const int* col1 = cols + (size_t)NNODE * SEGSTRIDE;
    const float* val0 = valsb;
    const float* val1 = valsb + (size_t)NNODE * SEGSTRIDE;

    // 0. weight repack + encoder
    k_repack<<<cdiv(32 * 128 * 9, T), T, 0, stream>>>(enc_w1, enc_w2, dec_w1, dec_w2,
                                                      wre1, wre2, wre3, wre4);
    k_conv_enc1<<<BB * 4 * PXB2, 256, 0, stream>>>(x, wre1, enc_b1, h1);
    k_conv_part<8><<<BB * 4 * 4 * PXB2, 256, 0, stream>>>(h1, wre2, nullptr, partial,
                                                          32, 32, 4, 4, 8, 0.0f);
    k_conv_reduce<<<cdiv(BB * 32 * NN, T), T, 0, stream>>>(partial, enc_b2, nullptr, xT_f0, 32, 4);
    // 1. adjacency
    k_build_adj<<<cdiv(2 * NNODE * SEGS, 4), 256, 0, stream>>>(Slist, segb, cols, valsb);
    // 2. s1/s2 on f0 for d0 + s0
    k_s1s2T<32><<<cdiv(NNODE, 16), 256, 0, stream>>>(xT_f0, d0_a, s1_d0, s2_d0,
                                                     s0_a, s1_s0, s2_s0);
    // 3. L1 merged: f1 = gat(f0,S0,d0); store z1_s0; emit d1,sc1
    k_gat_layer<32,16,1, 1,0, 2, 1><<<NNODE / 4, 256, 0, stream>>>(
        xT_f0, segb0, col0, val0,
        s1_d0, s2_d0, s1_s0, s2_s0, z1_s0,
        d0_W, d0_b, nullptr, nullptr, nullptr, nullptr,
        d1_a, s1_d1, s2_d1, s1_a, s1_sc1, s2_sc1, xT_f1);
    // 4. L2 merged: f2 = gat(f1,S1,d1); store z1_sc1; emit u0
    k_gat_layer<64,8,1, 1,0, 1, 1><<<NNODE / 4, 256, 0, stream>>>(
        xT_f1, segb1, col1, val1,
        s1_d1, s2_d1, s1_sc1, s2_sc1, z1_sc1,
        d1_W, d1_b, nullptr, nullptr, nullptr, nullptr,
        u0_a, s1_u0, s2_u0, nullptr, nullptr, nullptr, xT_f2);
    // 5. L3 merged: g1 = gat(f2,S1,u0) + proj(f1, z1_sc1); emit u1
    k_gat_layer<32,16,0, 64,1, 1, 2><<<NNODE / 4, 256, 0, stream>>>(
        xT_f2, segb1, col1, val1,
        s1_u0, s2_u0, nullptr, nullptr, nullptr,
        u0_W, u0_b, xT_f1, z1_sc1, s1_W, s1_b,
        u1_a, s1_u1, s2_u1, nullptr, nullptr, nullptr, xT_g1);
    // 6. L4 sparse: z1_u1 on (g1,S0)
    k_zgather<64,0><<<NNODE / 4, 256, 0, stream>>>(xT_g1, segb0, col0, val0,
                                                   s1_u1, s2_u1, z1_u1,
                                                   nullptr, nullptr, nullptr);
    // 7. L4 dense: g2 = proj(g1,z1_u1) + proj(f0,z1_s0), head-split (channel-major)
    k_dense_psplit<64,32,32,1,1><<<cdiv(NNODE, 8) * PP, 256, 0, stream>>>(
        xT_g1, z1_u1, u1_W, u1_b, xT_f0, z1_s0, s0_W, s0_b, g2);
    // 8. channel attention (scale fused into dec conv1)
    k_attmax<<<BB * 128, 64, 0, stream>>>(g2, att);
    k_camlp<<<BB, 128, 0, stream>>>(att, ca_w1, ca_b1, ca_w2, ca_b2, attf);
    // 9. decoder convs (pad -999)
    k_conv_part<8><<<BB * 8 * 4 * PXB2, 256, 0, stream>>>(g2, wre3, attf, partial,
                                                          128, 32, 4, 8, 16, -999.0f);
    k_conv_reduce<<<cdiv(BB * 32 * NN, T), T, 0, stream>>>(partial, dec_b1, dec1o, nullptr, 32, 8);
    k_conv_dec2<<<BB * PXB2, 256, 0, stream>>>(dec1o, wre4, dec_b2, dec2o);
    // 10. MLP head
    k_mlp1<<<BB * 512, 64, 0, stream>>>(dec2o, mlp_w1, mlp_b1, mbuf);
    k_mlp2<<<BB * 5, 64, 0, stream>>>(mbuf, mlp_w2, mlp_b2, out);
}